// Round 8
// baseline (3586.980 us; speedup 1.0000x reference)
//
#include <hip/hip_runtime.h>
#include <hip/hip_bf16.h>
#include <cstdint>
#include <cstddef>

#define F_DIM 128
#define P_DIM 2048
#define RADIUS 4
#define HT_STRIDE 136   // ushorts per row: 272 B = 16B-aligned rows for b128 frag reads
#define LOG2E 1.4426950408889634f

typedef short s16x8 __attribute__((ext_vector_type(8)));
typedef float f32x4 __attribute__((ext_vector_type(4)));

static __device__ __forceinline__ float bf2f(ushort u) {
    union { float f; uint i; } v; v.i = ((uint)u) << 16; return v.f;
}
static __device__ __forceinline__ ushort f2bf(float f) {
    uint u = __float_as_uint(f);
    uint r = (u + 0x7fffu + ((u >> 16) & 1u)) >> 16;   // RTN-even
    return (ushort)r;
}
static __device__ __forceinline__ f32x4 mfma16(s16x8 a, s16x8 b, f32x4 c) {
    return __builtin_amdgcn_mfma_f32_16x16x32_bf16(a, b, c, 0, 0, 0);
}

// ---------------- CSR build (once per launch) ----------------

__global__ void hist_kernel(const int* __restrict__ dst, int* __restrict__ counts, int E) {
    int e = blockIdx.x * blockDim.x + threadIdx.x;
    if (e < E) atomicAdd(&counts[dst[e]], 1);
}

__global__ __launch_bounds__(1024) void scan_kernel(const int* __restrict__ counts,
                                                    int* __restrict__ offs, int N) {
    __shared__ int buf[2][1024];
    __shared__ int carry_s;
    if (threadIdx.x == 0) carry_s = 0;
    __syncthreads();
    int nChunks = (N + 1023) >> 10;
    for (int c = 0; c < nChunks; ++c) {
        int i = (c << 10) + threadIdx.x;
        int v = (i < N) ? counts[i] : 0;
        int src = 0;
        buf[0][threadIdx.x] = v;
        __syncthreads();
        for (int off = 1; off < 1024; off <<= 1) {
            int d = src ^ 1;
            int val = buf[src][threadIdx.x];
            if (threadIdx.x >= (unsigned)off) val += buf[src][threadIdx.x - off];
            buf[d][threadIdx.x] = val;
            src = d;
            __syncthreads();
        }
        int inc = buf[src][threadIdx.x];
        if (i < N) offs[i + 1] = carry_s + inc;
        __syncthreads();
        if (threadIdx.x == 1023) carry_s += buf[src][1023];
        __syncthreads();
    }
    if (threadIdx.x == 0) offs[0] = 0;
}

__global__ void copy_kernel(const int* __restrict__ offs, int* __restrict__ cursor, int N) {
    int i = blockIdx.x * blockDim.x + threadIdx.x;
    if (i < N) cursor[i] = offs[i];
}

__global__ void scatter_kernel(const int* __restrict__ src, const int* __restrict__ dst,
                               int* __restrict__ cursor, int* __restrict__ srcs_sorted, int E) {
    int e = blockIdx.x * blockDim.x + threadIdx.x;
    if (e < E) {
        int d = dst[e];
        int pos = atomicAdd(&cursor[d], 1);
        srcs_sorted[pos] = src[e];
    }
}

// ---------------- one-time converts ----------------

__global__ void cvt_bf16_kernel(const float* __restrict__ src, ushort* __restrict__ dst, int n) {
    int i = blockIdx.x * blockDim.x + threadIdx.x;
    if (i < n) dst[i] = f2bf(src[i]);
}

__global__ void scale_kernel(const float* __restrict__ src, float* __restrict__ dst,
                             int n, float scale) {
    int i = blockIdx.x * blockDim.x + threadIdx.x;
    if (i < n) dst[i] = src[i] * scale;
}

// split fp32 W[K=128][P] (times scale) into hi+lo bf16, swizzled to MFMA B-frag order:
// dst[(((pt*4 + kt)*2 + s)*64 + lane)*8 + j] = split_s(scale*W[kt*32 + (lane>>4)*8 + j][pt*16 + (lane&15)])
__global__ void swizzle_split_kernel(const float* __restrict__ src, ushort* __restrict__ dst,
                                     int P, int total, float scale) {
    int d = blockIdx.x * blockDim.x + threadIdx.x;
    if (d >= total) return;
    int j    = d & 7;
    int lane = (d >> 3) & 63;
    int s    = (d >> 9) & 1;
    int kt   = (d >> 10) & 3;
    int pt   = d >> 12;
    int k = kt * 32 + (lane >> 4) * 8 + j;
    int p = pt * 16 + (lane & 15);
    float w = src[k * P + p] * scale;
    ushort hi = f2bf(w);
    ushort out = hi;
    if (s) out = f2bf(w - bf2f(hi));
    dst[d] = out;
}

// ---------------- aggregate (bf16 in, fp32 accum, bf16 out) ----------------
// one wave per node, uint (2×bf16) per lane

__global__ __launch_bounds__(256) void agg_kernel(const ushort* __restrict__ x,
                                                  const int* __restrict__ offs,
                                                  const int* __restrict__ srcs,
                                                  ushort* __restrict__ agg, int N) {
    int wid = (blockIdx.x * blockDim.x + threadIdx.x) >> 6;
    int lane = threadIdx.x & 63;
    if (wid >= N) return;
    const uint* xr = (const uint*)x;
    uint v = xr[(size_t)wid * 64 + lane];
    float a0 = bf2f((ushort)(v & 0xffffu));
    float a1 = bf2f((ushort)(v >> 16));
    int e0 = offs[wid], e1 = offs[wid + 1];
    for (int e = e0; e < e1; ++e) {
        uint u = xr[(size_t)srcs[e] * 64 + lane];
        a0 += bf2f((ushort)(u & 0xffffu));
        a1 += bf2f((ushort)(u >> 16));
    }
    ((uint*)agg)[(size_t)wid * 64 + lane] = ((uint)f2bf(a1) << 16) | (uint)f2bf(a0);
}

// ---------------- fused round ----------------
// block = 256 threads = 4 waves sharing ONE 64-node tile; wave w owns the P-range
// [32w, 32w+32). Keeps 64-node arithmetic intensity (32 MFMA : 8 B-loads) and
// round-6 per-block B-traffic while offering 4x the waves (6250 total).
// Softmax: per-wave partial (m,s) -> 2 KB LDS exchange (overlaying dead hT) ->
// cross-wave merge -> bbk. Disjoint pt ownership => pass 2 writes straight to
// global fp (no fp_s). One exp2 per logit in pass 1.

__global__ __launch_bounds__(256, 4) void round_kernel(
        const ushort* __restrict__ agg,    // [N,128] bf16
        const ushort* __restrict__ w1sw,   // swizzled hi/lo bf16 (natural scale)
        const float*  __restrict__ b1,
        const ushort* __restrict__ w2sw,   // swizzled hi/lo bf16, scaled by log2e
        const float*  __restrict__ b2l,    // b2 * log2e
        ushort* __restrict__ h_out,        // [N,128] bf16 (next round x)
        float* __restrict__ fp,            // [2048]
        int N) {
    __shared__ ushort smem_u[64 * HT_STRIDE];  // 17.4 KB; hT, later (m,s) merge buf
    ushort* hT = smem_u;
    float* mbuf = (float*)smem_u;              // [64][4] after hT is dead
    float* sbuf = ((float*)smem_u) + 256;      // [64][4]

    const int tid = threadIdx.x;
    const int w = tid >> 6;
    const int lane = tid & 63;
    const int q = lane >> 4;
    const int l15 = lane & 15;
    const int nodeBase = blockIdx.x * 64;
    const int ptBase = w * 32;

    const s16x8* w1v = (const s16x8*)w1sw;   // frag index: (pt*8 + kt*2 + s)*64 + lane
    const s16x8* w2v = (const s16x8*)w2sw;

    // ---- A-frags from global agg (all 4 waves load the same tile; L1-served) ----
    s16x8 a[4][4];
    #pragma unroll
    for (int g = 0; g < 4; ++g) {
        int node = nodeBase + g * 16 + l15;
        #pragma unroll
        for (int kt = 0; kt < 4; ++kt) {
            if (node < N)
                a[g][kt] = *(const s16x8*)(agg + (size_t)node * F_DIM + kt * 32 + q * 8);
            else
                a[g][kt] = (s16x8){0, 0, 0, 0, 0, 0, 0, 0};
        }
    }

    // ---- lin1: wave w computes feature tiles 2w, 2w+1 (h = relu(agg@W1+b1)) ----
    #pragma unroll
    for (int t = 0; t < 2; ++t) {
        int pt = 2 * w + t;
        f32x4 c[4];
        #pragma unroll
        for (int g = 0; g < 4; ++g) c[g] = (f32x4){0.f, 0.f, 0.f, 0.f};
        #pragma unroll
        for (int kt = 0; kt < 4; ++kt) {
            s16x8 bh = w1v[(size_t)(pt * 8 + kt * 2 + 0) * 64 + lane];
            s16x8 bl = w1v[(size_t)(pt * 8 + kt * 2 + 1) * 64 + lane];
            #pragma unroll
            for (int g = 0; g < 4; ++g) {
                c[g] = mfma16(a[g][kt], bh, c[g]);
                c[g] = mfma16(a[g][kt], bl, c[g]);
            }
        }
        float bb = b1[pt * 16 + l15];
        #pragma unroll
        for (int g = 0; g < 4; ++g)
            #pragma unroll
            for (int r = 0; r < 4; ++r) {
                float v = c[g][r] + bb;
                v = v > 0.f ? v : 0.f;
                hT[(g * 16 + q * 4 + r) * HT_STRIDE + pt * 16 + l15] = f2bf(v);
            }
    }
    __syncthreads();

    // ---- coalesced hT -> h_out: 64 rows x 16 chunks over 256 threads ----
    #pragma unroll
    for (int it = 0; it < 4; ++it) {
        int idx = it * 256 + tid;      // 0..1023
        int row = idx >> 4;            // 0..63
        int chunk = idx & 15;          // 0..15
        int gnode = nodeBase + row;
        if (gnode < N) {
            s16x8 vv = *(const s16x8*)&hT[row * HT_STRIDE + chunk * 8];
            *(s16x8*)(h_out + (size_t)gnode * F_DIM + chunk * 8) = vv;
        }
    }

    // ---- lin2 A-frags from hT (reuse a[][]) ----
    #pragma unroll
    for (int g = 0; g < 4; ++g)
        #pragma unroll
        for (int kt = 0; kt < 4; ++kt)
            a[g][kt] = *(const s16x8*)&hT[(g * 16 + l15) * HT_STRIDE + kt * 32 + q * 8];
    __syncthreads();   // hT dead everywhere; allow (m,s) overlay

    // ---- pass 1: online max / sum-exp2 over the wave's 32 pts, ping-pong B ----
    float m_[16], s_[16];
    #pragma unroll
    for (int j = 0; j < 16; ++j) { m_[j] = -INFINITY; s_[j] = 0.f; }

    s16x8 bA[8], bB[8];
    float bbA, bbB;
    #pragma unroll
    for (int f = 0; f < 8; ++f) bA[f] = w2v[(size_t)(ptBase * 8 + f) * 64 + lane];
    bbA = b2l[ptBase * 16 + l15];

    for (int pti = 0; pti < 32; pti += 2) {
        int pt = ptBase + pti;
        #pragma unroll
        for (int f = 0; f < 8; ++f) bB[f] = w2v[(size_t)((pt + 1) * 8 + f) * 64 + lane];
        bbB = b2l[(pt + 1) * 16 + l15];
        {   // compute pt with bA
            f32x4 c[4];
            #pragma unroll
            for (int g = 0; g < 4; ++g) c[g] = (f32x4){0.f, 0.f, 0.f, 0.f};
            #pragma unroll
            for (int kt = 0; kt < 4; ++kt) {
                #pragma unroll
                for (int g = 0; g < 4; ++g) c[g] = mfma16(a[g][kt], bA[kt * 2 + 0], c[g]);
                #pragma unroll
                for (int g = 0; g < 4; ++g) c[g] = mfma16(a[g][kt], bA[kt * 2 + 1], c[g]);
            }
            #pragma unroll
            for (int g = 0; g < 4; ++g)
                #pragma unroll
                for (int r = 0; r < 4; ++r) {
                    int j = g * 4 + r;
                    float v = c[g][r] + bbA;
                    float d = v - m_[j];
                    float e = exp2f(-fabsf(d));          // one exp per logit
                    float t1 = s_[j] + e;                // v <= m
                    float t2 = fmaf(s_[j], e, 1.0f);     // v >  m
                    bool up = d > 0.f;
                    s_[j] = up ? t2 : t1;
                    m_[j] = up ? v : m_[j];
                }
        }
        int pt2 = ptBase + ((pti + 2) & 31);   // wrap: harmless reload
        #pragma unroll
        for (int f = 0; f < 8; ++f) bA[f] = w2v[(size_t)(pt2 * 8 + f) * 64 + lane];
        bbA = b2l[pt2 * 16 + l15];
        {   // compute pt+1 with bB
            f32x4 c[4];
            #pragma unroll
            for (int g = 0; g < 4; ++g) c[g] = (f32x4){0.f, 0.f, 0.f, 0.f};
            #pragma unroll
            for (int kt = 0; kt < 4; ++kt) {
                #pragma unroll
                for (int g = 0; g < 4; ++g) c[g] = mfma16(a[g][kt], bB[kt * 2 + 0], c[g]);
                #pragma unroll
                for (int g = 0; g < 4; ++g) c[g] = mfma16(a[g][kt], bB[kt * 2 + 1], c[g]);
            }
            #pragma unroll
            for (int g = 0; g < 4; ++g)
                #pragma unroll
                for (int r = 0; r < 4; ++r) {
                    int j = g * 4 + r;
                    float v = c[g][r] + bbB;
                    float d = v - m_[j];
                    float e = exp2f(-fabsf(d));
                    float t1 = s_[j] + e;
                    float t2 = fmaf(s_[j], e, 1.0f);
                    bool up = d > 0.f;
                    s_[j] = up ? t2 : t1;
                    m_[j] = up ? v : m_[j];
                }
        }
    }

    // ---- intra-wave merge across 16 p-lanes; publish per-wave partials ----
    #pragma unroll
    for (int j = 0; j < 16; ++j) {
        float mm = m_[j], ss = s_[j];
        #pragma unroll
        for (int off = 1; off <= 8; off <<= 1) {
            float om = __shfl_xor(mm, off);
            float os = __shfl_xor(ss, off);
            float nm = fmaxf(mm, om);
            ss = ss * exp2f(mm - nm) + os * exp2f(om - nm);
            mm = nm;
        }
        if (l15 == 0) {
            int node = (j >> 2) * 16 + q * 4 + (j & 3);
            mbuf[node * 4 + w] = mm;
            sbuf[node * 4 + w] = ss;
        }
    }
    __syncthreads();

    // ---- cross-wave merge -> bbk = -m - log2(s) ----
    float bbk[16];
    #pragma unroll
    for (int j = 0; j < 16; ++j) {
        int node = (j >> 2) * 16 + q * 4 + (j & 3);
        float4 mv = *(const float4*)&mbuf[node * 4];
        float4 sv = *(const float4*)&sbuf[node * 4];
        float nm = fmaxf(fmaxf(mv.x, mv.y), fmaxf(mv.z, mv.w));
        float ss = sv.x * exp2f(mv.x - nm) + sv.y * exp2f(mv.y - nm)
                 + sv.z * exp2f(mv.z - nm) + sv.w * exp2f(mv.w - nm);
        bbk[j] = (nodeBase + node < N) ? (-nm - __log2f(ss)) : -INFINITY;
    }

    // ---- pass 2: recompute the wave's 32 pts, atomics straight to global fp ----
    #pragma unroll
    for (int f = 0; f < 8; ++f) bA[f] = w2v[(size_t)(ptBase * 8 + f) * 64 + lane];
    bbA = b2l[ptBase * 16 + l15];

    for (int pti = 0; pti < 32; pti += 2) {
        int pt = ptBase + pti;
        #pragma unroll
        for (int f = 0; f < 8; ++f) bB[f] = w2v[(size_t)((pt + 1) * 8 + f) * 64 + lane];
        bbB = b2l[(pt + 1) * 16 + l15];
        {   // pt with bA
            f32x4 c[4];
            #pragma unroll
            for (int g = 0; g < 4; ++g) c[g] = (f32x4){0.f, 0.f, 0.f, 0.f};
            #pragma unroll
            for (int kt = 0; kt < 4; ++kt) {
                #pragma unroll
                for (int g = 0; g < 4; ++g) c[g] = mfma16(a[g][kt], bA[kt * 2 + 0], c[g]);
                #pragma unroll
                for (int g = 0; g < 4; ++g) c[g] = mfma16(a[g][kt], bA[kt * 2 + 1], c[g]);
            }
            float tot = 0.f;
            #pragma unroll
            for (int g = 0; g < 4; ++g)
                #pragma unroll
                for (int r = 0; r < 4; ++r)
                    tot += exp2f(c[g][r] + bbA + bbk[g * 4 + r]);
            tot += __shfl_xor(tot, 16);
            tot += __shfl_xor(tot, 32);
            if (lane < 16) atomicAdd(&fp[pt * 16 + lane], tot);
        }
        int pt2 = ptBase + ((pti + 2) & 31);
        #pragma unroll
        for (int f = 0; f < 8; ++f) bA[f] = w2v[(size_t)(pt2 * 8 + f) * 64 + lane];
        bbA = b2l[pt2 * 16 + l15];
        {   // pt+1 with bB
            f32x4 c[4];
            #pragma unroll
            for (int g = 0; g < 4; ++g) c[g] = (f32x4){0.f, 0.f, 0.f, 0.f};
            #pragma unroll
            for (int kt = 0; kt < 4; ++kt) {
                #pragma unroll
                for (int g = 0; g < 4; ++g) c[g] = mfma16(a[g][kt], bB[kt * 2 + 0], c[g]);
                #pragma unroll
                for (int g = 0; g < 4; ++g) c[g] = mfma16(a[g][kt], bB[kt * 2 + 1], c[g]);
            }
            float tot = 0.f;
            #pragma unroll
            for (int g = 0; g < 4; ++g)
                #pragma unroll
                for (int r = 0; r < 4; ++r)
                    tot += exp2f(c[g][r] + bbB + bbk[g * 4 + r]);
            tot += __shfl_xor(tot, 16);
            tot += __shfl_xor(tot, 32);
            if (lane < 16) atomicAdd(&fp[(pt + 1) * 16 + lane], tot);
        }
    }
}

// ---------------- launcher ----------------

extern "C" void kernel_launch(void* const* d_in, const int* in_sizes, int n_in,
                              void* d_out, int out_size, void* d_ws, size_t ws_size,
                              hipStream_t stream) {
    const float* atoms = (const float*)d_in[0];
    const float* W1    = (const float*)d_in[1];
    const float* b1    = (const float*)d_in[2];
    const float* W2    = (const float*)d_in[3];
    const float* b2    = (const float*)d_in[4];
    const int* esrc    = (const int*)d_in[5];
    const int* edst    = (const int*)d_in[6];
    float* fp          = (float*)d_out;
    const int N = in_sizes[0] / F_DIM;
    const int E = in_sizes[5];

    char* ws = (char*)d_ws;
    ushort* xA   = (ushort*)ws;  ws += (size_t)N * F_DIM * sizeof(ushort);
    ushort* xB   = (ushort*)ws;  ws += (size_t)N * F_DIM * sizeof(ushort);
    ushort* aggb = (ushort*)ws;  ws += (size_t)N * F_DIM * sizeof(ushort);
    ushort* w1sw = (ushort*)ws;  ws += (size_t)F_DIM * F_DIM * 2 * sizeof(ushort);
    ushort* w2sw = (ushort*)ws;  ws += (size_t)F_DIM * P_DIM * 2 * sizeof(ushort);
    float*  b2l  = (float*)ws;   ws += (size_t)P_DIM * sizeof(float);
    int* offs    = (int*)ws;     ws += (((size_t)(N + 1) * sizeof(int) + 255) & ~255ull);
    int* cursor  = (int*)ws;     ws += (((size_t)N * sizeof(int) + 255) & ~255ull);
    int* srcs    = (int*)ws;

    hipMemsetAsync(d_out, 0, (size_t)out_size * sizeof(float), stream);
    hipMemsetAsync(cursor, 0, (size_t)N * sizeof(int), stream);

    // CSR build
    int eb = (E + 255) / 256;
    hist_kernel<<<eb, 256, 0, stream>>>(edst, cursor, E);
    scan_kernel<<<1, 1024, 0, stream>>>(cursor, offs, N);
    copy_kernel<<<(N + 255) / 256, 256, 0, stream>>>(offs, cursor, N);
    scatter_kernel<<<eb, 256, 0, stream>>>(esrc, edst, cursor, srcs, E);

    // one-time converts
    int nconv = N * F_DIM;
    cvt_bf16_kernel<<<(nconv + 255) / 256, 256, 0, stream>>>(atoms, xA, nconv);
    int t1 = F_DIM * F_DIM * 2;
    swizzle_split_kernel<<<(t1 + 255) / 256, 256, 0, stream>>>(W1, w1sw, F_DIM, t1, 1.0f);
    int t2 = F_DIM * P_DIM * 2;
    swizzle_split_kernel<<<(t2 + 255) / 256, 256, 0, stream>>>(W2, w2sw, P_DIM, t2, LOG2E);
    scale_kernel<<<(P_DIM + 255) / 256, 256, 0, stream>>>(b2, b2l, P_DIM, LOG2E);

    const ushort* x = xA;
    ushort* xnext = xB;
    int rblocks = (N + 63) / 64;
    for (int r = 0; r < RADIUS; ++r) {
        agg_kernel<<<(N + 3) / 4, 256, 0, stream>>>(x, offs, srcs, aggb, N);
        round_kernel<<<rblocks, 256, 0, stream>>>(aggb, w1sw, b1, w2sw, b2l,
                                                  xnext, fp, N);
        x = xnext;
        xnext = (xnext == xB) ? xA : xB;
    }
}

// Round 9
// 2944.604 us; speedup vs baseline: 1.2182x; 1.2182x over previous
//
#include <hip/hip_runtime.h>
#include <hip/hip_bf16.h>
#include <cstdint>
#include <cstddef>

#define F_DIM 128
#define P_DIM 2048
#define RADIUS 4
#define HT_STRIDE 136   // ushorts per row: 272 B = 16B-aligned rows for b128 frag reads
#define LOG2E 1.4426950408889634f

typedef short s16x8 __attribute__((ext_vector_type(8)));
typedef float f32x4 __attribute__((ext_vector_type(4)));

static __device__ __forceinline__ float bf2f(ushort u) {
    union { float f; uint i; } v; v.i = ((uint)u) << 16; return v.f;
}
static __device__ __forceinline__ ushort f2bf(float f) {
    uint u = __float_as_uint(f);
    uint r = (u + 0x7fffu + ((u >> 16) & 1u)) >> 16;   // RTN-even
    return (ushort)r;
}
static __device__ __forceinline__ f32x4 mfma16(s16x8 a, s16x8 b, f32x4 c) {
    return __builtin_amdgcn_mfma_f32_16x16x32_bf16(a, b, c, 0, 0, 0);
}

// ---------------- CSR build (once per launch) ----------------

__global__ void hist_kernel(const int* __restrict__ dst, int* __restrict__ counts, int E) {
    int e = blockIdx.x * blockDim.x + threadIdx.x;
    if (e < E) atomicAdd(&counts[dst[e]], 1);
}

__global__ __launch_bounds__(1024) void scan_kernel(const int* __restrict__ counts,
                                                    int* __restrict__ offs, int N) {
    __shared__ int buf[2][1024];
    __shared__ int carry_s;
    if (threadIdx.x == 0) carry_s = 0;
    __syncthreads();
    int nChunks = (N + 1023) >> 10;
    for (int c = 0; c < nChunks; ++c) {
        int i = (c << 10) + threadIdx.x;
        int v = (i < N) ? counts[i] : 0;
        int src = 0;
        buf[0][threadIdx.x] = v;
        __syncthreads();
        for (int off = 1; off < 1024; off <<= 1) {
            int d = src ^ 1;
            int val = buf[src][threadIdx.x];
            if (threadIdx.x >= (unsigned)off) val += buf[src][threadIdx.x - off];
            buf[d][threadIdx.x] = val;
            src = d;
            __syncthreads();
        }
        int inc = buf[src][threadIdx.x];
        if (i < N) offs[i + 1] = carry_s + inc;
        __syncthreads();
        if (threadIdx.x == 1023) carry_s += buf[src][1023];
        __syncthreads();
    }
    if (threadIdx.x == 0) offs[0] = 0;
}

__global__ void copy_kernel(const int* __restrict__ offs, int* __restrict__ cursor, int N) {
    int i = blockIdx.x * blockDim.x + threadIdx.x;
    if (i < N) cursor[i] = offs[i];
}

__global__ void scatter_kernel(const int* __restrict__ src, const int* __restrict__ dst,
                               int* __restrict__ cursor, int* __restrict__ srcs_sorted, int E) {
    int e = blockIdx.x * blockDim.x + threadIdx.x;
    if (e < E) {
        int d = dst[e];
        int pos = atomicAdd(&cursor[d], 1);
        srcs_sorted[pos] = src[e];
    }
}

// ---------------- one-time converts ----------------

__global__ void cvt_bf16_kernel(const float* __restrict__ src, ushort* __restrict__ dst, int n) {
    int i = blockIdx.x * blockDim.x + threadIdx.x;
    if (i < n) dst[i] = f2bf(src[i]);
}

__global__ void scale_kernel(const float* __restrict__ src, float* __restrict__ dst,
                             int n, float scale) {
    int i = blockIdx.x * blockDim.x + threadIdx.x;
    if (i < n) dst[i] = src[i] * scale;
}

// split fp32 W[K=128][P] (times scale) into hi+lo bf16, swizzled to MFMA B-frag order:
// dst[(((pt*4 + kt)*2 + s)*64 + lane)*8 + j] = split_s(scale*W[kt*32 + (lane>>4)*8 + j][pt*16 + (lane&15)])
__global__ void swizzle_split_kernel(const float* __restrict__ src, ushort* __restrict__ dst,
                                     int P, int total, float scale) {
    int d = blockIdx.x * blockDim.x + threadIdx.x;
    if (d >= total) return;
    int j    = d & 7;
    int lane = (d >> 3) & 63;
    int s    = (d >> 9) & 1;
    int kt   = (d >> 10) & 3;
    int pt   = d >> 12;
    int k = kt * 32 + (lane >> 4) * 8 + j;
    int p = pt * 16 + (lane & 15);
    float w = src[k * P + p] * scale;
    ushort hi = f2bf(w);
    ushort out = hi;
    if (s) out = f2bf(w - bf2f(hi));
    dst[d] = out;
}

// ---------------- aggregate (bf16 in, fp32 accum, bf16 out) ----------------
// one wave per node, uint (2×bf16) per lane

__global__ __launch_bounds__(256) void agg_kernel(const ushort* __restrict__ x,
                                                  const int* __restrict__ offs,
                                                  const int* __restrict__ srcs,
                                                  ushort* __restrict__ agg, int N) {
    int wid = (blockIdx.x * blockDim.x + threadIdx.x) >> 6;
    int lane = threadIdx.x & 63;
    if (wid >= N) return;
    const uint* xr = (const uint*)x;
    uint v = xr[(size_t)wid * 64 + lane];
    float a0 = bf2f((ushort)(v & 0xffffu));
    float a1 = bf2f((ushort)(v >> 16));
    int e0 = offs[wid], e1 = offs[wid + 1];
    for (int e = e0; e < e1; ++e) {
        uint u = xr[(size_t)srcs[e] * 64 + lane];
        a0 += bf2f((ushort)(u & 0xffffu));
        a1 += bf2f((ushort)(u >> 16));
    }
    ((uint*)agg)[(size_t)wid * 64 + lane] = ((uint)f2bf(a1) << 16) | (uint)f2bf(a0);
}

// ---------------- fused round ----------------
// block = 256 threads = 4 waves sharing ONE 64-node tile; wave w owns the P-range
// [32w, 32w+32). 64-node arithmetic intensity (32 MFMA : 8 B-loads), round-6
// per-block B-traffic, 4x the waves (6250). __launch_bounds__(256,3): VGPR cap
// 170 so the ~160-reg pipeline (a[4][4] + bA/bB ping-pong) FITS — (256,4)'s
// 128 cap spilled A-frags to scratch (round 8: FETCH 1.14 GB, VGPR=64).

__global__ __launch_bounds__(256, 3) void round_kernel(
        const ushort* __restrict__ agg,    // [N,128] bf16
        const ushort* __restrict__ w1sw,   // swizzled hi/lo bf16 (natural scale)
        const float*  __restrict__ b1,
        const ushort* __restrict__ w2sw,   // swizzled hi/lo bf16, scaled by log2e
        const float*  __restrict__ b2l,    // b2 * log2e
        ushort* __restrict__ h_out,        // [N,128] bf16 (next round x)
        float* __restrict__ fp,            // [2048]
        int N) {
    __shared__ ushort smem_u[64 * HT_STRIDE];  // 17.4 KB; hT, later (m,s) merge buf
    ushort* hT = smem_u;
    float* mbuf = (float*)smem_u;              // [64][4] after hT is dead
    float* sbuf = ((float*)smem_u) + 256;      // [64][4]

    const int tid = threadIdx.x;
    const int w = tid >> 6;
    const int lane = tid & 63;
    const int q = lane >> 4;
    const int l15 = lane & 15;
    const int nodeBase = blockIdx.x * 64;
    const int ptBase = w * 32;

    const s16x8* w1v = (const s16x8*)w1sw;   // frag index: (pt*8 + kt*2 + s)*64 + lane
    const s16x8* w2v = (const s16x8*)w2sw;

    // ---- A-frags from global agg (all 4 waves load the same tile; L1-served) ----
    s16x8 a[4][4];
    #pragma unroll
    for (int g = 0; g < 4; ++g) {
        int node = nodeBase + g * 16 + l15;
        #pragma unroll
        for (int kt = 0; kt < 4; ++kt) {
            if (node < N)
                a[g][kt] = *(const s16x8*)(agg + (size_t)node * F_DIM + kt * 32 + q * 8);
            else
                a[g][kt] = (s16x8){0, 0, 0, 0, 0, 0, 0, 0};
        }
    }

    // ---- lin1: wave w computes feature tiles 2w, 2w+1 (h = relu(agg@W1+b1)) ----
    #pragma unroll
    for (int t = 0; t < 2; ++t) {
        int pt = 2 * w + t;
        f32x4 c[4];
        #pragma unroll
        for (int g = 0; g < 4; ++g) c[g] = (f32x4){0.f, 0.f, 0.f, 0.f};
        #pragma unroll
        for (int kt = 0; kt < 4; ++kt) {
            s16x8 bh = w1v[(size_t)(pt * 8 + kt * 2 + 0) * 64 + lane];
            s16x8 bl = w1v[(size_t)(pt * 8 + kt * 2 + 1) * 64 + lane];
            #pragma unroll
            for (int g = 0; g < 4; ++g) {
                c[g] = mfma16(a[g][kt], bh, c[g]);
                c[g] = mfma16(a[g][kt], bl, c[g]);
            }
        }
        float bb = b1[pt * 16 + l15];
        #pragma unroll
        for (int g = 0; g < 4; ++g)
            #pragma unroll
            for (int r = 0; r < 4; ++r) {
                float v = c[g][r] + bb;
                v = v > 0.f ? v : 0.f;
                hT[(g * 16 + q * 4 + r) * HT_STRIDE + pt * 16 + l15] = f2bf(v);
            }
    }
    __syncthreads();

    // ---- coalesced hT -> h_out: 64 rows x 16 chunks over 256 threads ----
    #pragma unroll
    for (int it = 0; it < 4; ++it) {
        int idx = it * 256 + tid;      // 0..1023
        int row = idx >> 4;            // 0..63
        int chunk = idx & 15;          // 0..15
        int gnode = nodeBase + row;
        if (gnode < N) {
            s16x8 vv = *(const s16x8*)&hT[row * HT_STRIDE + chunk * 8];
            *(s16x8*)(h_out + (size_t)gnode * F_DIM + chunk * 8) = vv;
        }
    }

    // ---- lin2 A-frags from hT (reuse a[][]) ----
    #pragma unroll
    for (int g = 0; g < 4; ++g)
        #pragma unroll
        for (int kt = 0; kt < 4; ++kt)
            a[g][kt] = *(const s16x8*)&hT[(g * 16 + l15) * HT_STRIDE + kt * 32 + q * 8];
    __syncthreads();   // hT dead everywhere; allow (m,s) overlay

    // ---- pass 1: online max / sum-exp2 over the wave's 32 pts, ping-pong B ----
    float m_[16], s_[16];
    #pragma unroll
    for (int j = 0; j < 16; ++j) { m_[j] = -INFINITY; s_[j] = 0.f; }

    s16x8 bA[8], bB[8];
    float bbA, bbB;
    #pragma unroll
    for (int f = 0; f < 8; ++f) bA[f] = w2v[(size_t)(ptBase * 8 + f) * 64 + lane];
    bbA = b2l[ptBase * 16 + l15];

    for (int pti = 0; pti < 32; pti += 2) {
        int pt = ptBase + pti;
        #pragma unroll
        for (int f = 0; f < 8; ++f) bB[f] = w2v[(size_t)((pt + 1) * 8 + f) * 64 + lane];
        bbB = b2l[(pt + 1) * 16 + l15];
        {   // compute pt with bA
            f32x4 c[4];
            #pragma unroll
            for (int g = 0; g < 4; ++g) c[g] = (f32x4){0.f, 0.f, 0.f, 0.f};
            #pragma unroll
            for (int kt = 0; kt < 4; ++kt) {
                #pragma unroll
                for (int g = 0; g < 4; ++g) c[g] = mfma16(a[g][kt], bA[kt * 2 + 0], c[g]);
                #pragma unroll
                for (int g = 0; g < 4; ++g) c[g] = mfma16(a[g][kt], bA[kt * 2 + 1], c[g]);
            }
            #pragma unroll
            for (int g = 0; g < 4; ++g)
                #pragma unroll
                for (int r = 0; r < 4; ++r) {
                    int j = g * 4 + r;
                    float v = c[g][r] + bbA;
                    float d = v - m_[j];
                    float e = exp2f(-fabsf(d));          // one exp per logit
                    float t1 = s_[j] + e;                // v <= m
                    float t2 = fmaf(s_[j], e, 1.0f);     // v >  m
                    bool up = d > 0.f;
                    s_[j] = up ? t2 : t1;
                    m_[j] = up ? v : m_[j];
                }
        }
        int pt2 = ptBase + ((pti + 2) & 31);   // wrap: harmless reload
        #pragma unroll
        for (int f = 0; f < 8; ++f) bA[f] = w2v[(size_t)(pt2 * 8 + f) * 64 + lane];
        bbA = b2l[pt2 * 16 + l15];
        {   // compute pt+1 with bB
            f32x4 c[4];
            #pragma unroll
            for (int g = 0; g < 4; ++g) c[g] = (f32x4){0.f, 0.f, 0.f, 0.f};
            #pragma unroll
            for (int kt = 0; kt < 4; ++kt) {
                #pragma unroll
                for (int g = 0; g < 4; ++g) c[g] = mfma16(a[g][kt], bB[kt * 2 + 0], c[g]);
                #pragma unroll
                for (int g = 0; g < 4; ++g) c[g] = mfma16(a[g][kt], bB[kt * 2 + 1], c[g]);
            }
            #pragma unroll
            for (int g = 0; g < 4; ++g)
                #pragma unroll
                for (int r = 0; r < 4; ++r) {
                    int j = g * 4 + r;
                    float v = c[g][r] + bbB;
                    float d = v - m_[j];
                    float e = exp2f(-fabsf(d));
                    float t1 = s_[j] + e;
                    float t2 = fmaf(s_[j], e, 1.0f);
                    bool up = d > 0.f;
                    s_[j] = up ? t2 : t1;
                    m_[j] = up ? v : m_[j];
                }
        }
    }

    // ---- intra-wave merge across 16 p-lanes; publish per-wave partials ----
    #pragma unroll
    for (int j = 0; j < 16; ++j) {
        float mm = m_[j], ss = s_[j];
        #pragma unroll
        for (int off = 1; off <= 8; off <<= 1) {
            float om = __shfl_xor(mm, off);
            float os = __shfl_xor(ss, off);
            float nm = fmaxf(mm, om);
            ss = ss * exp2f(mm - nm) + os * exp2f(om - nm);
            mm = nm;
        }
        if (l15 == 0) {
            int node = (j >> 2) * 16 + q * 4 + (j & 3);
            mbuf[node * 4 + w] = mm;
            sbuf[node * 4 + w] = ss;
        }
    }
    __syncthreads();

    // ---- cross-wave merge -> bbk = -m - log2(s) ----
    float bbk[16];
    #pragma unroll
    for (int j = 0; j < 16; ++j) {
        int node = (j >> 2) * 16 + q * 4 + (j & 3);
        float4 mv = *(const float4*)&mbuf[node * 4];
        float4 sv = *(const float4*)&sbuf[node * 4];
        float nm = fmaxf(fmaxf(mv.x, mv.y), fmaxf(mv.z, mv.w));
        float ss = sv.x * exp2f(mv.x - nm) + sv.y * exp2f(mv.y - nm)
                 + sv.z * exp2f(mv.z - nm) + sv.w * exp2f(mv.w - nm);
        bbk[j] = (nodeBase + node < N) ? (-nm - __log2f(ss)) : -INFINITY;
    }

    // ---- pass 2: recompute the wave's 32 pts, atomics straight to global fp ----
    #pragma unroll
    for (int f = 0; f < 8; ++f) bA[f] = w2v[(size_t)(ptBase * 8 + f) * 64 + lane];
    bbA = b2l[ptBase * 16 + l15];

    for (int pti = 0; pti < 32; pti += 2) {
        int pt = ptBase + pti;
        #pragma unroll
        for (int f = 0; f < 8; ++f) bB[f] = w2v[(size_t)((pt + 1) * 8 + f) * 64 + lane];
        bbB = b2l[(pt + 1) * 16 + l15];
        {   // pt with bA
            f32x4 c[4];
            #pragma unroll
            for (int g = 0; g < 4; ++g) c[g] = (f32x4){0.f, 0.f, 0.f, 0.f};
            #pragma unroll
            for (int kt = 0; kt < 4; ++kt) {
                #pragma unroll
                for (int g = 0; g < 4; ++g) c[g] = mfma16(a[g][kt], bA[kt * 2 + 0], c[g]);
                #pragma unroll
                for (int g = 0; g < 4; ++g) c[g] = mfma16(a[g][kt], bA[kt * 2 + 1], c[g]);
            }
            float tot = 0.f;
            #pragma unroll
            for (int g = 0; g < 4; ++g)
                #pragma unroll
                for (int r = 0; r < 4; ++r)
                    tot += exp2f(c[g][r] + bbA + bbk[g * 4 + r]);
            tot += __shfl_xor(tot, 16);
            tot += __shfl_xor(tot, 32);
            if (lane < 16) atomicAdd(&fp[pt * 16 + lane], tot);
        }
        int pt2 = ptBase + ((pti + 2) & 31);
        #pragma unroll
        for (int f = 0; f < 8; ++f) bA[f] = w2v[(size_t)(pt2 * 8 + f) * 64 + lane];
        bbA = b2l[pt2 * 16 + l15];
        {   // pt+1 with bB
            f32x4 c[4];
            #pragma unroll
            for (int g = 0; g < 4; ++g) c[g] = (f32x4){0.f, 0.f, 0.f, 0.f};
            #pragma unroll
            for (int kt = 0; kt < 4; ++kt) {
                #pragma unroll
                for (int g = 0; g < 4; ++g) c[g] = mfma16(a[g][kt], bB[kt * 2 + 0], c[g]);
                #pragma unroll
                for (int g = 0; g < 4; ++g) c[g] = mfma16(a[g][kt], bB[kt * 2 + 1], c[g]);
            }
            float tot = 0.f;
            #pragma unroll
            for (int g = 0; g < 4; ++g)
                #pragma unroll
                for (int r = 0; r < 4; ++r)
                    tot += exp2f(c[g][r] + bbB + bbk[g * 4 + r]);
            tot += __shfl_xor(tot, 16);
            tot += __shfl_xor(tot, 32);
            if (lane < 16) atomicAdd(&fp[(pt + 1) * 16 + lane], tot);
        }
    }
}

// ---------------- launcher ----------------

extern "C" void kernel_launch(void* const* d_in, const int* in_sizes, int n_in,
                              void* d_out, int out_size, void* d_ws, size_t ws_size,
                              hipStream_t stream) {
    const float* atoms = (const float*)d_in[0];
    const float* W1    = (const float*)d_in[1];
    const float* b1    = (const float*)d_in[2];
    const float* W2    = (const float*)d_in[3];
    const float* b2    = (const float*)d_in[4];
    const int* esrc    = (const int*)d_in[5];
    const int* edst    = (const int*)d_in[6];
    float* fp          = (float*)d_out;
    const int N = in_sizes[0] / F_DIM;
    const int E = in_sizes[5];

    char* ws = (char*)d_ws;
    ushort* xA   = (ushort*)ws;  ws += (size_t)N * F_DIM * sizeof(ushort);
    ushort* xB   = (ushort*)ws;  ws += (size_t)N * F_DIM * sizeof(ushort);
    ushort* aggb = (ushort*)ws;  ws += (size_t)N * F_DIM * sizeof(ushort);
    ushort* w1sw = (ushort*)ws;  ws += (size_t)F_DIM * F_DIM * 2 * sizeof(ushort);
    ushort* w2sw = (ushort*)ws;  ws += (size_t)F_DIM * P_DIM * 2 * sizeof(ushort);
    float*  b2l  = (float*)ws;   ws += (size_t)P_DIM * sizeof(float);
    int* offs    = (int*)ws;     ws += (((size_t)(N + 1) * sizeof(int) + 255) & ~255ull);
    int* cursor  = (int*)ws;     ws += (((size_t)N * sizeof(int) + 255) & ~255ull);
    int* srcs    = (int*)ws;

    hipMemsetAsync(d_out, 0, (size_t)out_size * sizeof(float), stream);
    hipMemsetAsync(cursor, 0, (size_t)N * sizeof(int), stream);

    // CSR build
    int eb = (E + 255) / 256;
    hist_kernel<<<eb, 256, 0, stream>>>(edst, cursor, E);
    scan_kernel<<<1, 1024, 0, stream>>>(cursor, offs, N);
    copy_kernel<<<(N + 255) / 256, 256, 0, stream>>>(offs, cursor, N);
    scatter_kernel<<<eb, 256, 0, stream>>>(esrc, edst, cursor, srcs, E);

    // one-time converts
    int nconv = N * F_DIM;
    cvt_bf16_kernel<<<(nconv + 255) / 256, 256, 0, stream>>>(atoms, xA, nconv);
    int t1 = F_DIM * F_DIM * 2;
    swizzle_split_kernel<<<(t1 + 255) / 256, 256, 0, stream>>>(W1, w1sw, F_DIM, t1, 1.0f);
    int t2 = F_DIM * P_DIM * 2;
    swizzle_split_kernel<<<(t2 + 255) / 256, 256, 0, stream>>>(W2, w2sw, P_DIM, t2, LOG2E);
    scale_kernel<<<(P_DIM + 255) / 256, 256, 0, stream>>>(b2, b2l, P_DIM, LOG2E);

    const ushort* x = xA;
    ushort* xnext = xB;
    int rblocks = (N + 63) / 64;
    for (int r = 0; r < RADIUS; ++r) {
        agg_kernel<<<(N + 3) / 4, 256, 0, stream>>>(x, offs, srcs, aggb, N);
        round_kernel<<<rblocks, 256, 0, stream>>>(aggb, w1sw, b1, w2sw, b2l,
                                                  xnext, fp, N);
        x = xnext;
        xnext = (xnext == xB) ? xA : xB;
    }
}

// Round 10
// 2268.736 us; speedup vs baseline: 1.5810x; 1.2979x over previous
//
#include <hip/hip_runtime.h>
#include <hip/hip_bf16.h>
#include <cstdint>
#include <cstddef>

#define F_DIM 128
#define P_DIM 2048
#define RADIUS 4
#define HT_STRIDE 136   // ushorts per row: 272 B = 16B-aligned rows for b128 frag reads
#define LOG2E 1.4426950408889634f

typedef short s16x8 __attribute__((ext_vector_type(8)));
typedef float f32x4 __attribute__((ext_vector_type(4)));

static __device__ __forceinline__ float bf2f(ushort u) {
    union { float f; uint i; } v; v.i = ((uint)u) << 16; return v.f;
}
static __device__ __forceinline__ ushort f2bf(float f) {
    uint u = __float_as_uint(f);
    uint r = (u + 0x7fffu + ((u >> 16) & 1u)) >> 16;   // RTN-even
    return (ushort)r;
}
static __device__ __forceinline__ f32x4 mfma16(s16x8 a, s16x8 b, f32x4 c) {
    return __builtin_amdgcn_mfma_f32_16x16x32_bf16(a, b, c, 0, 0, 0);
}

// ---------------- CSR build (once per launch) ----------------

__global__ void hist_kernel(const int* __restrict__ dst, int* __restrict__ counts, int E) {
    int e = blockIdx.x * blockDim.x + threadIdx.x;
    if (e < E) atomicAdd(&counts[dst[e]], 1);
}

__global__ __launch_bounds__(1024) void scan_kernel(const int* __restrict__ counts,
                                                    int* __restrict__ offs, int N) {
    __shared__ int buf[2][1024];
    __shared__ int carry_s;
    if (threadIdx.x == 0) carry_s = 0;
    __syncthreads();
    int nChunks = (N + 1023) >> 10;
    for (int c = 0; c < nChunks; ++c) {
        int i = (c << 10) + threadIdx.x;
        int v = (i < N) ? counts[i] : 0;
        int src = 0;
        buf[0][threadIdx.x] = v;
        __syncthreads();
        for (int off = 1; off < 1024; off <<= 1) {
            int d = src ^ 1;
            int val = buf[src][threadIdx.x];
            if (threadIdx.x >= (unsigned)off) val += buf[src][threadIdx.x - off];
            buf[d][threadIdx.x] = val;
            src = d;
            __syncthreads();
        }
        int inc = buf[src][threadIdx.x];
        if (i < N) offs[i + 1] = carry_s + inc;
        __syncthreads();
        if (threadIdx.x == 1023) carry_s += buf[src][1023];
        __syncthreads();
    }
    if (threadIdx.x == 0) offs[0] = 0;
}

__global__ void copy_kernel(const int* __restrict__ offs, int* __restrict__ cursor, int N) {
    int i = blockIdx.x * blockDim.x + threadIdx.x;
    if (i < N) cursor[i] = offs[i];
}

__global__ void scatter_kernel(const int* __restrict__ src, const int* __restrict__ dst,
                               int* __restrict__ cursor, int* __restrict__ srcs_sorted, int E) {
    int e = blockIdx.x * blockDim.x + threadIdx.x;
    if (e < E) {
        int d = dst[e];
        int pos = atomicAdd(&cursor[d], 1);
        srcs_sorted[pos] = src[e];
    }
}

// ---------------- one-time converts ----------------

__global__ void cvt_bf16_kernel(const float* __restrict__ src, ushort* __restrict__ dst, int n) {
    int i = blockIdx.x * blockDim.x + threadIdx.x;
    if (i < n) dst[i] = f2bf(src[i]);
}

__global__ void scale_kernel(const float* __restrict__ src, float* __restrict__ dst,
                             int n, float scale) {
    int i = blockIdx.x * blockDim.x + threadIdx.x;
    if (i < n) dst[i] = src[i] * scale;
}

// split fp32 W[K=128][P] (times scale) into hi+lo bf16, swizzled to MFMA B-frag order:
// dst[(((pt*4 + kt)*2 + s)*64 + lane)*8 + j] = split_s(scale*W[kt*32 + (lane>>4)*8 + j][pt*16 + (lane&15)])
__global__ void swizzle_split_kernel(const float* __restrict__ src, ushort* __restrict__ dst,
                                     int P, int total, float scale) {
    int d = blockIdx.x * blockDim.x + threadIdx.x;
    if (d >= total) return;
    int j    = d & 7;
    int lane = (d >> 3) & 63;
    int s    = (d >> 9) & 1;
    int kt   = (d >> 10) & 3;
    int pt   = d >> 12;
    int k = kt * 32 + (lane >> 4) * 8 + j;
    int p = pt * 16 + (lane & 15);
    float w = src[k * P + p] * scale;
    ushort hi = f2bf(w);
    ushort out = hi;
    if (s) out = f2bf(w - bf2f(hi));
    dst[d] = out;
}

// ---------------- aggregate (bf16 in, fp32 accum, bf16 out) ----------------
// one wave per node, uint (2×bf16) per lane

__global__ __launch_bounds__(256) void agg_kernel(const ushort* __restrict__ x,
                                                  const int* __restrict__ offs,
                                                  const int* __restrict__ srcs,
                                                  ushort* __restrict__ agg, int N) {
    int wid = (blockIdx.x * blockDim.x + threadIdx.x) >> 6;
    int lane = threadIdx.x & 63;
    if (wid >= N) return;
    const uint* xr = (const uint*)x;
    uint v = xr[(size_t)wid * 64 + lane];
    float a0 = bf2f((ushort)(v & 0xffffu));
    float a1 = bf2f((ushort)(v >> 16));
    int e0 = offs[wid], e1 = offs[wid + 1];
    for (int e = e0; e < e1; ++e) {
        uint u = xr[(size_t)srcs[e] * 64 + lane];
        a0 += bf2f((ushort)(u & 0xffffu));
        a1 += bf2f((ushort)(u >> 16));
    }
    ((uint*)agg)[(size_t)wid * 64 + lane] = ((uint)f2bf(a1) << 16) | (uint)f2bf(a0);
}

// ---------------- fused round ----------------
// block = 256 threads = 4 waves sharing ONE 64-node tile; wave w owns the P-range
// [32w, 32w+32). NO register ping-pong: single B buffer keeps the working set at
// ~154 VGPRs so __launch_bounds__(256,3)'s 170 cap holds WITHOUT spilling
// (rounds 8/9: ping-pong pushed it to ~196 -> A-frag spills, FETCH 1.14GB/81MB).
// Latency hiding comes from 3 resident waves/SIMD (TLP), not ILP.

__global__ __launch_bounds__(256, 3) void round_kernel(
        const ushort* __restrict__ agg,    // [N,128] bf16
        const ushort* __restrict__ w1sw,   // swizzled hi/lo bf16 (natural scale)
        const float*  __restrict__ b1,
        const ushort* __restrict__ w2sw,   // swizzled hi/lo bf16, scaled by log2e
        const float*  __restrict__ b2l,    // b2 * log2e
        ushort* __restrict__ h_out,        // [N,128] bf16 (next round x)
        float* __restrict__ fp,            // [2048]
        int N) {
    __shared__ ushort smem_u[64 * HT_STRIDE];  // 17.4 KB; hT, later (m,s) merge buf
    ushort* hT = smem_u;
    float* mbuf = (float*)smem_u;              // [64][4] after hT is dead
    float* sbuf = ((float*)smem_u) + 256;      // [64][4]

    const int tid = threadIdx.x;
    const int w = tid >> 6;
    const int lane = tid & 63;
    const int q = lane >> 4;
    const int l15 = lane & 15;
    const int nodeBase = blockIdx.x * 64;
    const int ptBase = w * 32;

    const s16x8* w1v = (const s16x8*)w1sw;   // frag index: (pt*8 + kt*2 + s)*64 + lane
    const s16x8* w2v = (const s16x8*)w2sw;

    // ---- A-frags from global agg (all 4 waves load the same tile; L1-served) ----
    s16x8 a[4][4];
    #pragma unroll
    for (int g = 0; g < 4; ++g) {
        int node = nodeBase + g * 16 + l15;
        #pragma unroll
        for (int kt = 0; kt < 4; ++kt) {
            if (node < N)
                a[g][kt] = *(const s16x8*)(agg + (size_t)node * F_DIM + kt * 32 + q * 8);
            else
                a[g][kt] = (s16x8){0, 0, 0, 0, 0, 0, 0, 0};
        }
    }

    // ---- lin1: wave w computes feature tiles 2w, 2w+1 (h = relu(agg@W1+b1)) ----
    #pragma unroll
    for (int t = 0; t < 2; ++t) {
        int pt = 2 * w + t;
        f32x4 c[4];
        #pragma unroll
        for (int g = 0; g < 4; ++g) c[g] = (f32x4){0.f, 0.f, 0.f, 0.f};
        #pragma unroll
        for (int kt = 0; kt < 4; ++kt) {
            s16x8 bh = w1v[(size_t)(pt * 8 + kt * 2 + 0) * 64 + lane];
            s16x8 bl = w1v[(size_t)(pt * 8 + kt * 2 + 1) * 64 + lane];
            #pragma unroll
            for (int g = 0; g < 4; ++g) {
                c[g] = mfma16(a[g][kt], bh, c[g]);
                c[g] = mfma16(a[g][kt], bl, c[g]);
            }
        }
        float bb = b1[pt * 16 + l15];
        #pragma unroll
        for (int g = 0; g < 4; ++g)
            #pragma unroll
            for (int r = 0; r < 4; ++r) {
                float v = c[g][r] + bb;
                v = v > 0.f ? v : 0.f;
                hT[(g * 16 + q * 4 + r) * HT_STRIDE + pt * 16 + l15] = f2bf(v);
            }
    }
    __syncthreads();

    // ---- coalesced hT -> h_out: 64 rows x 16 chunks over 256 threads ----
    #pragma unroll
    for (int it = 0; it < 4; ++it) {
        int idx = it * 256 + tid;      // 0..1023
        int row = idx >> 4;            // 0..63
        int chunk = idx & 15;          // 0..15
        int gnode = nodeBase + row;
        if (gnode < N) {
            s16x8 vv = *(const s16x8*)&hT[row * HT_STRIDE + chunk * 8];
            *(s16x8*)(h_out + (size_t)gnode * F_DIM + chunk * 8) = vv;
        }
    }

    // ---- lin2 A-frags from hT (reuse a[][]) ----
    #pragma unroll
    for (int g = 0; g < 4; ++g)
        #pragma unroll
        for (int kt = 0; kt < 4; ++kt)
            a[g][kt] = *(const s16x8*)&hT[(g * 16 + l15) * HT_STRIDE + kt * 32 + q * 8];
    __syncthreads();   // hT dead everywhere; allow (m,s) overlay

    // ---- pass 1: online max / sum-exp2 over the wave's 32 pts ----
    float m_[16], s_[16];
    #pragma unroll
    for (int j = 0; j < 16; ++j) { m_[j] = -INFINITY; s_[j] = 0.f; }

    for (int pti = 0; pti < 32; ++pti) {
        int pt = ptBase + pti;
        s16x8 b[8];
        #pragma unroll
        for (int f = 0; f < 8; ++f) b[f] = w2v[(size_t)(pt * 8 + f) * 64 + lane];
        float bb = b2l[pt * 16 + l15];
        f32x4 c[4];
        #pragma unroll
        for (int g = 0; g < 4; ++g) c[g] = (f32x4){0.f, 0.f, 0.f, 0.f};
        #pragma unroll
        for (int kt = 0; kt < 4; ++kt) {
            #pragma unroll
            for (int g = 0; g < 4; ++g) c[g] = mfma16(a[g][kt], b[kt * 2 + 0], c[g]);
            #pragma unroll
            for (int g = 0; g < 4; ++g) c[g] = mfma16(a[g][kt], b[kt * 2 + 1], c[g]);
        }
        #pragma unroll
        for (int g = 0; g < 4; ++g)
            #pragma unroll
            for (int r = 0; r < 4; ++r) {
                int j = g * 4 + r;
                float v = c[g][r] + bb;
                float d = v - m_[j];
                float e = exp2f(-fabsf(d));          // one exp per logit
                float t1 = s_[j] + e;                // v <= m
                float t2 = fmaf(s_[j], e, 1.0f);     // v >  m
                bool up = d > 0.f;
                s_[j] = up ? t2 : t1;
                m_[j] = up ? v : m_[j];
            }
    }

    // ---- intra-wave merge across 16 p-lanes; publish per-wave partials ----
    #pragma unroll
    for (int j = 0; j < 16; ++j) {
        float mm = m_[j], ss = s_[j];
        #pragma unroll
        for (int off = 1; off <= 8; off <<= 1) {
            float om = __shfl_xor(mm, off);
            float os = __shfl_xor(ss, off);
            float nm = fmaxf(mm, om);
            ss = ss * exp2f(mm - nm) + os * exp2f(om - nm);
            mm = nm;
        }
        if (l15 == 0) {
            int node = (j >> 2) * 16 + q * 4 + (j & 3);
            mbuf[node * 4 + w] = mm;
            sbuf[node * 4 + w] = ss;
        }
    }
    __syncthreads();

    // ---- cross-wave merge -> bbk = -m - log2(s) ----
    float bbk[16];
    #pragma unroll
    for (int j = 0; j < 16; ++j) {
        int node = (j >> 2) * 16 + q * 4 + (j & 3);
        float4 mv = *(const float4*)&mbuf[node * 4];
        float4 sv = *(const float4*)&sbuf[node * 4];
        float nm = fmaxf(fmaxf(mv.x, mv.y), fmaxf(mv.z, mv.w));
        float ss = sv.x * exp2f(mv.x - nm) + sv.y * exp2f(mv.y - nm)
                 + sv.z * exp2f(mv.z - nm) + sv.w * exp2f(mv.w - nm);
        bbk[j] = (nodeBase + node < N) ? (-nm - __log2f(ss)) : -INFINITY;
    }

    // ---- pass 2: recompute the wave's 32 pts, atomics straight to global fp ----
    for (int pti = 0; pti < 32; ++pti) {
        int pt = ptBase + pti;
        s16x8 b[8];
        #pragma unroll
        for (int f = 0; f < 8; ++f) b[f] = w2v[(size_t)(pt * 8 + f) * 64 + lane];
        float bb = b2l[pt * 16 + l15];
        f32x4 c[4];
        #pragma unroll
        for (int g = 0; g < 4; ++g) c[g] = (f32x4){0.f, 0.f, 0.f, 0.f};
        #pragma unroll
        for (int kt = 0; kt < 4; ++kt) {
            #pragma unroll
            for (int g = 0; g < 4; ++g) c[g] = mfma16(a[g][kt], b[kt * 2 + 0], c[g]);
            #pragma unroll
            for (int g = 0; g < 4; ++g) c[g] = mfma16(a[g][kt], b[kt * 2 + 1], c[g]);
        }
        float tot = 0.f;
        #pragma unroll
        for (int g = 0; g < 4; ++g)
            #pragma unroll
            for (int r = 0; r < 4; ++r)
                tot += exp2f(c[g][r] + bb + bbk[g * 4 + r]);
        tot += __shfl_xor(tot, 16);
        tot += __shfl_xor(tot, 32);
        if (lane < 16) atomicAdd(&fp[pt * 16 + lane], tot);
    }
}

// ---------------- launcher ----------------

extern "C" void kernel_launch(void* const* d_in, const int* in_sizes, int n_in,
                              void* d_out, int out_size, void* d_ws, size_t ws_size,
                              hipStream_t stream) {
    const float* atoms = (const float*)d_in[0];
    const float* W1    = (const float*)d_in[1];
    const float* b1    = (const float*)d_in[2];
    const float* W2    = (const float*)d_in[3];
    const float* b2    = (const float*)d_in[4];
    const int* esrc    = (const int*)d_in[5];
    const int* edst    = (const int*)d_in[6];
    float* fp          = (float*)d_out;
    const int N = in_sizes[0] / F_DIM;
    const int E = in_sizes[5];

    char* ws = (char*)d_ws;
    ushort* xA   = (ushort*)ws;  ws += (size_t)N * F_DIM * sizeof(ushort);
    ushort* xB   = (ushort*)ws;  ws += (size_t)N * F_DIM * sizeof(ushort);
    ushort* aggb = (ushort*)ws;  ws += (size_t)N * F_DIM * sizeof(ushort);
    ushort* w1sw = (ushort*)ws;  ws += (size_t)F_DIM * F_DIM * 2 * sizeof(ushort);
    ushort* w2sw = (ushort*)ws;  ws += (size_t)F_DIM * P_DIM * 2 * sizeof(ushort);
    float*  b2l  = (float*)ws;   ws += (size_t)P_DIM * sizeof(float);
    int* offs    = (int*)ws;     ws += (((size_t)(N + 1) * sizeof(int) + 255) & ~255ull);
    int* cursor  = (int*)ws;     ws += (((size_t)N * sizeof(int) + 255) & ~255ull);
    int* srcs    = (int*)ws;

    hipMemsetAsync(d_out, 0, (size_t)out_size * sizeof(float), stream);
    hipMemsetAsync(cursor, 0, (size_t)N * sizeof(int), stream);

    // CSR build
    int eb = (E + 255) / 256;
    hist_kernel<<<eb, 256, 0, stream>>>(edst, cursor, E);
    scan_kernel<<<1, 1024, 0, stream>>>(cursor, offs, N);
    copy_kernel<<<(N + 255) / 256, 256, 0, stream>>>(offs, cursor, N);
    scatter_kernel<<<eb, 256, 0, stream>>>(esrc, edst, cursor, srcs, E);

    // one-time converts
    int nconv = N * F_DIM;
    cvt_bf16_kernel<<<(nconv + 255) / 256, 256, 0, stream>>>(atoms, xA, nconv);
    int t1 = F_DIM * F_DIM * 2;
    swizzle_split_kernel<<<(t1 + 255) / 256, 256, 0, stream>>>(W1, w1sw, F_DIM, t1, 1.0f);
    int t2 = F_DIM * P_DIM * 2;
    swizzle_split_kernel<<<(t2 + 255) / 256, 256, 0, stream>>>(W2, w2sw, P_DIM, t2, LOG2E);
    scale_kernel<<<(P_DIM + 255) / 256, 256, 0, stream>>>(b2, b2l, P_DIM, LOG2E);

    const ushort* x = xA;
    ushort* xnext = xB;
    int rblocks = (N + 63) / 64;
    for (int r = 0; r < RADIUS; ++r) {
        agg_kernel<<<(N + 3) / 4, 256, 0, stream>>>(x, offs, srcs, aggb, N);
        round_kernel<<<rblocks, 256, 0, stream>>>(aggb, w1sw, b1, w2sw, b2l,
                                                  xnext, fp, N);
        x = xnext;
        xnext = (xnext == xB) ? xA : xB;
    }
}

// Round 11
// 2268.618 us; speedup vs baseline: 1.5811x; 1.0001x over previous
//
#include <hip/hip_runtime.h>
#include <hip/hip_bf16.h>
#include <cstdint>
#include <cstddef>

#define F_DIM 128
#define P_DIM 2048
#define RADIUS 4
#define HT_STRIDE 136   // ushorts per row: 272 B = 16B-aligned rows for b128 frag reads
#define LOG2E 1.4426950408889634f
#define NTILE 256       // nodes per block-tile (4 waves x 64)

typedef short s16x8 __attribute__((ext_vector_type(8)));
typedef float f32x4 __attribute__((ext_vector_type(4)));

static __device__ __forceinline__ float bf2f(ushort u) {
    union { float f; uint i; } v; v.i = ((uint)u) << 16; return v.f;
}
static __device__ __forceinline__ ushort f2bf(float f) {
    uint u = __float_as_uint(f);
    uint r = (u + 0x7fffu + ((u >> 16) & 1u)) >> 16;   // RTN-even
    return (ushort)r;
}
static __device__ __forceinline__ f32x4 mfma16(s16x8 a, s16x8 b, f32x4 c) {
    return __builtin_amdgcn_mfma_f32_16x16x32_bf16(a, b, c, 0, 0, 0);
}

// ---------------- CSR build (once per launch) ----------------

__global__ void hist_kernel(const int* __restrict__ dst, int* __restrict__ counts, int E) {
    int e = blockIdx.x * blockDim.x + threadIdx.x;
    if (e < E) atomicAdd(&counts[dst[e]], 1);
}

__global__ __launch_bounds__(1024) void scan_kernel(const int* __restrict__ counts,
                                                    int* __restrict__ offs, int N) {
    __shared__ int buf[2][1024];
    __shared__ int carry_s;
    if (threadIdx.x == 0) carry_s = 0;
    __syncthreads();
    int nChunks = (N + 1023) >> 10;
    for (int c = 0; c < nChunks; ++c) {
        int i = (c << 10) + threadIdx.x;
        int v = (i < N) ? counts[i] : 0;
        int src = 0;
        buf[0][threadIdx.x] = v;
        __syncthreads();
        for (int off = 1; off < 1024; off <<= 1) {
            int d = src ^ 1;
            int val = buf[src][threadIdx.x];
            if (threadIdx.x >= (unsigned)off) val += buf[src][threadIdx.x - off];
            buf[d][threadIdx.x] = val;
            src = d;
            __syncthreads();
        }
        int inc = buf[src][threadIdx.x];
        if (i < N) offs[i + 1] = carry_s + inc;
        __syncthreads();
        if (threadIdx.x == 1023) carry_s += buf[src][1023];
        __syncthreads();
    }
    if (threadIdx.x == 0) offs[0] = 0;
}

__global__ void copy_kernel(const int* __restrict__ offs, int* __restrict__ cursor, int N) {
    int i = blockIdx.x * blockDim.x + threadIdx.x;
    if (i < N) cursor[i] = offs[i];
}

__global__ void scatter_kernel(const int* __restrict__ src, const int* __restrict__ dst,
                               int* __restrict__ cursor, int* __restrict__ srcs_sorted, int E) {
    int e = blockIdx.x * blockDim.x + threadIdx.x;
    if (e < E) {
        int d = dst[e];
        int pos = atomicAdd(&cursor[d], 1);
        srcs_sorted[pos] = src[e];
    }
}

// ---------------- one-time converts ----------------

__global__ void cvt_bf16_kernel(const float* __restrict__ src, ushort* __restrict__ dst, int n) {
    int i = blockIdx.x * blockDim.x + threadIdx.x;
    if (i < n) dst[i] = f2bf(src[i]);
}

__global__ void scale_kernel(const float* __restrict__ src, float* __restrict__ dst,
                             int n, float scale) {
    int i = blockIdx.x * blockDim.x + threadIdx.x;
    if (i < n) dst[i] = src[i] * scale;
}

// split fp32 W[K=128][P] (times scale) into hi+lo bf16, swizzled to MFMA B-frag order:
// dst[(((pt*4 + kt)*2 + s)*64 + lane)*8 + j] = split_s(scale*W[kt*32 + (lane>>4)*8 + j][pt*16 + (lane&15)])
__global__ void swizzle_split_kernel(const float* __restrict__ src, ushort* __restrict__ dst,
                                     int P, int total, float scale) {
    int d = blockIdx.x * blockDim.x + threadIdx.x;
    if (d >= total) return;
    int j    = d & 7;
    int lane = (d >> 3) & 63;
    int s    = (d >> 9) & 1;
    int kt   = (d >> 10) & 3;
    int pt   = d >> 12;
    int k = kt * 32 + (lane >> 4) * 8 + j;
    int p = pt * 16 + (lane & 15);
    float w = src[k * P + p] * scale;
    ushort hi = f2bf(w);
    ushort out = hi;
    if (s) out = f2bf(w - bf2f(hi));
    dst[d] = out;
}

// ---------------- aggregate (bf16 in, fp32 accum, bf16 out) ----------------
// one wave per node, uint (2×bf16) per lane

__global__ __launch_bounds__(256) void agg_kernel(const ushort* __restrict__ x,
                                                  const int* __restrict__ offs,
                                                  const int* __restrict__ srcs,
                                                  ushort* __restrict__ agg, int N) {
    int wid = (blockIdx.x * blockDim.x + threadIdx.x) >> 6;
    int lane = threadIdx.x & 63;
    if (wid >= N) return;
    const uint* xr = (const uint*)x;
    uint v = xr[(size_t)wid * 64 + lane];
    float a0 = bf2f((ushort)(v & 0xffffu));
    float a1 = bf2f((ushort)(v >> 16));
    int e0 = offs[wid], e1 = offs[wid + 1];
    for (int e = e0; e < e1; ++e) {
        uint u = xr[(size_t)srcs[e] * 64 + lane];
        a0 += bf2f((ushort)(u & 0xffffu));
        a1 += bf2f((ushort)(u >> 16));
    }
    ((uint*)agg)[(size_t)wid * 64 + lane] = ((uint)f2bf(a1) << 16) | (uint)f2bf(a0);
}

// ---------------- fused round (persistent blocks, LDS-staged W2) ----------------
// 512 persistent blocks x 256 thr (4 waves x 64 nodes = 256 nodes/tile); tiles pulled
// from an atomic work queue (no co-residency required for correctness). All 4 waves
// sweep all 128 pts in lockstep; each pt's 8 KB W2 fragment block is staged ONCE into
// an LDS double-buffer (each wave stages 2 of 8 chunks) and ds_read by all 4 waves:
// L2 B-traffic /4 vs round 10. Per-block pt order staggered to decorrelate L2 lines.
// lin1 transpose via per-wave 16-node LDS buffers (wave-local, DS in-order, no sync).
// fp_s accumulated in LDS across tiles, flushed once per block.

__global__ __launch_bounds__(256, 2) void round_kernel(
        const ushort* __restrict__ agg,    // [N,128] bf16
        const ushort* __restrict__ w1sw,   // swizzled hi/lo bf16 (natural scale)
        const float*  __restrict__ b1,
        const ushort* __restrict__ w2sw,   // swizzled hi/lo bf16, scaled by log2e
        const float*  __restrict__ b2l,    // b2 * log2e
        ushort* __restrict__ h_out,        // [N,128] bf16 (next round x)
        float* __restrict__ fp,            // [2048]
        int N, int nTiles, int* __restrict__ counter) {
    __shared__ ushort stg[2][4096];            // 16 KB staging double-buffer
    __shared__ ushort hT16[4 * 16 * HT_STRIDE]; // 17.4 KB: per-wave 16-node transpose
    __shared__ float fp_s[P_DIM];              // 8 KB
    __shared__ int tile_s;

    const int tid = threadIdx.x;
    const int w = tid >> 6;
    const int lane = tid & 63;
    const int q = lane >> 4;
    const int l15 = lane & 15;
    const int c0 = 2 * w;                      // this wave's staging chunks
    ushort* myhT = &hT16[w * 16 * HT_STRIDE];

    const s16x8* w1v = (const s16x8*)w1sw;     // frag index: (pt*8 + kt*2 + s)*64 + lane
    const s16x8* w2v = (const s16x8*)w2sw;

    for (int i = tid; i < P_DIM; i += 256) fp_s[i] = 0.f;

    while (true) {
        __syncthreads();                       // guards tile_s / stg / hT16 reuse
        if (tid == 0) tile_s = atomicAdd(counter, 1);
        __syncthreads();
        const int tile = tile_s;
        if (tile >= nTiles) break;

        const int nodeBase = tile * NTILE + w * 64;
        const int ofs = (tile * 37) & 127;     // per-block pt-order stagger

        // ---- agg A-frags ----
        s16x8 a[4][4];
        #pragma unroll
        for (int g = 0; g < 4; ++g) {
            int node = nodeBase + g * 16 + l15;
            #pragma unroll
            for (int kt = 0; kt < 4; ++kt) {
                if (node < N)
                    a[g][kt] = *(const s16x8*)(agg + (size_t)node * F_DIM + kt * 32 + q * 8);
                else
                    a[g][kt] = (s16x8){0, 0, 0, 0, 0, 0, 0, 0};
            }
        }

        // ---- lin1 per g-tile: compute 16 nodes x 128 cols, transpose via myhT,
        //      reload lin2 A-frags (overwrites a[g][*]), store h_out coalesced ----
        #pragma unroll
        for (int g = 0; g < 4; ++g) {
            #pragma unroll
            for (int pt = 0; pt < 8; ++pt) {
                f32x4 c = {0.f, 0.f, 0.f, 0.f};
                #pragma unroll
                for (int kt = 0; kt < 4; ++kt) {
                    s16x8 bh = w1v[(size_t)(pt * 8 + kt * 2 + 0) * 64 + lane];
                    s16x8 bl = w1v[(size_t)(pt * 8 + kt * 2 + 1) * 64 + lane];
                    c = mfma16(a[g][kt], bh, c);
                    c = mfma16(a[g][kt], bl, c);
                }
                float bb = b1[pt * 16 + l15];
                #pragma unroll
                for (int r = 0; r < 4; ++r) {
                    float v = c[r] + bb;
                    v = v > 0.f ? v : 0.f;
                    myhT[(q * 4 + r) * HT_STRIDE + pt * 16 + l15] = f2bf(v);
                }
            }
            // wave-local: DS pipe in-order, no barrier needed
            #pragma unroll
            for (int kt = 0; kt < 4; ++kt)
                a[g][kt] = *(const s16x8*)&myhT[l15 * HT_STRIDE + kt * 32 + q * 8];
            // h_out rows g*16..g*16+15, coalesced b128
            #pragma unroll
            for (int it = 0; it < 4; ++it) {
                int idx = it * 64 + lane;          // 0..255
                int row = idx >> 4;                // 0..15
                int chunk = idx & 15;              // 0..15
                int gnode = nodeBase + g * 16 + row;
                if (gnode < N) {
                    s16x8 vv = *(const s16x8*)&myhT[row * HT_STRIDE + chunk * 8];
                    *(s16x8*)(h_out + (size_t)gnode * F_DIM + chunk * 8) = vv;
                }
            }
        }

        // ---- pass 1: online max / sum-exp2, W2 staged via LDS double-buffer ----
        float m_[16], s_[16];
        #pragma unroll
        for (int j = 0; j < 16; ++j) { m_[j] = -INFINITY; s_[j] = 0.f; }

        s16x8 t0, t1;
        {
            int pt0 = ofs;
            t0 = w2v[(size_t)(pt0 * 8 + c0) * 64 + lane];
            t1 = w2v[(size_t)(pt0 * 8 + c0 + 1) * 64 + lane];
            *(s16x8*)&stg[0][c0 * 512 + lane * 8] = t0;
            *(s16x8*)&stg[0][(c0 + 1) * 512 + lane * 8] = t1;
        }
        __syncthreads();
        for (int i = 0; i < 128; ++i) {
            int pt = (i + ofs) & 127;
            bool more = (i + 1 < 128);
            if (more) {
                int ptn = (i + 1 + ofs) & 127;
                t0 = w2v[(size_t)(ptn * 8 + c0) * 64 + lane];
                t1 = w2v[(size_t)(ptn * 8 + c0 + 1) * 64 + lane];
            }
            const ushort* cur = stg[i & 1];
            s16x8 b[8];
            #pragma unroll
            for (int f = 0; f < 8; ++f) b[f] = *(const s16x8*)&cur[f * 512 + lane * 8];
            float bb = b2l[pt * 16 + l15];
            f32x4 c[4];
            #pragma unroll
            for (int g = 0; g < 4; ++g) c[g] = (f32x4){0.f, 0.f, 0.f, 0.f};
            #pragma unroll
            for (int kt = 0; kt < 4; ++kt) {
                #pragma unroll
                for (int g = 0; g < 4; ++g) c[g] = mfma16(a[g][kt], b[kt * 2 + 0], c[g]);
                #pragma unroll
                for (int g = 0; g < 4; ++g) c[g] = mfma16(a[g][kt], b[kt * 2 + 1], c[g]);
            }
            #pragma unroll
            for (int g = 0; g < 4; ++g)
                #pragma unroll
                for (int r = 0; r < 4; ++r) {
                    int j = g * 4 + r;
                    float v = c[g][r] + bb;
                    float d = v - m_[j];
                    float e = exp2f(-fabsf(d));          // one exp per logit
                    float u1 = s_[j] + e;                // v <= m
                    float u2 = fmaf(s_[j], e, 1.0f);     // v >  m
                    bool up = d > 0.f;
                    s_[j] = up ? u2 : u1;
                    m_[j] = up ? v : m_[j];
                }
            if (more) {
                ushort* nxt = stg[(i + 1) & 1];
                *(s16x8*)&nxt[c0 * 512 + lane * 8] = t0;
                *(s16x8*)&nxt[(c0 + 1) * 512 + lane * 8] = t1;
            }
            __syncthreads();
        }

        // ---- per-wave merge across 16 p-lanes -> bbk = -m - log2(s) ----
        float bbk[16];
        #pragma unroll
        for (int j = 0; j < 16; ++j) {
            float mm = m_[j], ss = s_[j];
            #pragma unroll
            for (int off = 1; off <= 8; off <<= 1) {
                float om = __shfl_xor(mm, off);
                float os = __shfl_xor(ss, off);
                float nm = fmaxf(mm, om);
                ss = ss * exp2f(mm - nm) + os * exp2f(om - nm);
                mm = nm;
            }
            int node = nodeBase + (j >> 2) * 16 + q * 4 + (j & 3);
            bbk[j] = (node < N) ? (-mm - __log2f(ss)) : -INFINITY;
        }

        // ---- pass 2: recompute logits, accumulate normalized probs into fp_s ----
        {
            int pt0 = ofs;
            t0 = w2v[(size_t)(pt0 * 8 + c0) * 64 + lane];
            t1 = w2v[(size_t)(pt0 * 8 + c0 + 1) * 64 + lane];
            *(s16x8*)&stg[0][c0 * 512 + lane * 8] = t0;
            *(s16x8*)&stg[0][(c0 + 1) * 512 + lane * 8] = t1;
        }
        __syncthreads();
        for (int i = 0; i < 128; ++i) {
            int pt = (i + ofs) & 127;
            bool more = (i + 1 < 128);
            if (more) {
                int ptn = (i + 1 + ofs) & 127;
                t0 = w2v[(size_t)(ptn * 8 + c0) * 64 + lane];
                t1 = w2v[(size_t)(ptn * 8 + c0 + 1) * 64 + lane];
            }
            const ushort* cur = stg[i & 1];
            s16x8 b[8];
            #pragma unroll
            for (int f = 0; f < 8; ++f) b[f] = *(const s16x8*)&cur[f * 512 + lane * 8];
            float bb = b2l[pt * 16 + l15];
            f32x4 c[4];
            #pragma unroll
            for (int g = 0; g < 4; ++g) c[g] = (f32x4){0.f, 0.f, 0.f, 0.f};
            #pragma unroll
            for (int kt = 0; kt < 4; ++kt) {
                #pragma unroll
                for (int g = 0; g < 4; ++g) c[g] = mfma16(a[g][kt], b[kt * 2 + 0], c[g]);
                #pragma unroll
                for (int g = 0; g < 4; ++g) c[g] = mfma16(a[g][kt], b[kt * 2 + 1], c[g]);
            }
            float tot = 0.f;
            #pragma unroll
            for (int g = 0; g < 4; ++g)
                #pragma unroll
                for (int r = 0; r < 4; ++r)
                    tot += exp2f(c[g][r] + bb + bbk[g * 4 + r]);
            tot += __shfl_xor(tot, 16);
            tot += __shfl_xor(tot, 32);
            if (lane < 16) atomicAdd(&fp_s[pt * 16 + lane], tot);
            if (more) {
                ushort* nxt = stg[(i + 1) & 1];
                *(s16x8*)&nxt[c0 * 512 + lane * 8] = t0;
                *(s16x8*)&nxt[(c0 + 1) * 512 + lane * 8] = t1;
            }
            __syncthreads();
        }
    }

    // ---- flush block-accumulated fingerprint ----
    for (int i = tid; i < P_DIM; i += 256) atomicAdd(&fp[i], fp_s[i]);
}

// ---------------- launcher ----------------

extern "C" void kernel_launch(void* const* d_in, const int* in_sizes, int n_in,
                              void* d_out, int out_size, void* d_ws, size_t ws_size,
                              hipStream_t stream) {
    const float* atoms = (const float*)d_in[0];
    const float* W1    = (const float*)d_in[1];
    const float* b1    = (const float*)d_in[2];
    const float* W2    = (const float*)d_in[3];
    const float* b2    = (const float*)d_in[4];
    const int* esrc    = (const int*)d_in[5];
    const int* edst    = (const int*)d_in[6];
    float* fp          = (float*)d_out;
    const int N = in_sizes[0] / F_DIM;
    const int E = in_sizes[5];

    char* ws = (char*)d_ws;
    ushort* xA   = (ushort*)ws;  ws += (size_t)N * F_DIM * sizeof(ushort);
    ushort* xB   = (ushort*)ws;  ws += (size_t)N * F_DIM * sizeof(ushort);
    ushort* aggb = (ushort*)ws;  ws += (size_t)N * F_DIM * sizeof(ushort);
    ushort* w1sw = (ushort*)ws;  ws += (size_t)F_DIM * F_DIM * 2 * sizeof(ushort);
    ushort* w2sw = (ushort*)ws;  ws += (size_t)F_DIM * P_DIM * 2 * sizeof(ushort);
    float*  b2l  = (float*)ws;   ws += (size_t)P_DIM * sizeof(float);
    int* counters = (int*)ws;    ws += 256;   // 4 round work-queue counters (padded)
    int* offs    = (int*)ws;     ws += (((size_t)(N + 1) * sizeof(int) + 255) & ~255ull);
    int* cursor  = (int*)ws;     ws += (((size_t)N * sizeof(int) + 255) & ~255ull);
    int* srcs    = (int*)ws;

    hipMemsetAsync(d_out, 0, (size_t)out_size * sizeof(float), stream);
    hipMemsetAsync(cursor, 0, (size_t)N * sizeof(int), stream);
    hipMemsetAsync(counters, 0, 256, stream);

    // CSR build
    int eb = (E + 255) / 256;
    hist_kernel<<<eb, 256, 0, stream>>>(edst, cursor, E);
    scan_kernel<<<1, 1024, 0, stream>>>(cursor, offs, N);
    copy_kernel<<<(N + 255) / 256, 256, 0, stream>>>(offs, cursor, N);
    scatter_kernel<<<eb, 256, 0, stream>>>(esrc, edst, cursor, srcs, E);

    // one-time converts
    int nconv = N * F_DIM;
    cvt_bf16_kernel<<<(nconv + 255) / 256, 256, 0, stream>>>(atoms, xA, nconv);
    int t1 = F_DIM * F_DIM * 2;
    swizzle_split_kernel<<<(t1 + 255) / 256, 256, 0, stream>>>(W1, w1sw, F_DIM, t1, 1.0f);
    int t2 = F_DIM * P_DIM * 2;
    swizzle_split_kernel<<<(t2 + 255) / 256, 256, 0, stream>>>(W2, w2sw, P_DIM, t2, LOG2E);
    scale_kernel<<<(P_DIM + 255) / 256, 256, 0, stream>>>(b2, b2l, P_DIM, LOG2E);

    const ushort* x = xA;
    ushort* xnext = xB;
    int nTiles = (N + NTILE - 1) / NTILE;
    for (int r = 0; r < RADIUS; ++r) {
        agg_kernel<<<(N + 3) / 4, 256, 0, stream>>>(x, offs, srcs, aggb, N);
        round_kernel<<<512, 256, 0, stream>>>(aggb, w1sw, b1, w2sw, b2l,
                                              xnext, fp, N, nTiles, counters + r);
        x = xnext;
        xnext = (xnext == xB) ? xA : xB;
    }
}

// Round 12
// 1931.292 us; speedup vs baseline: 1.8573x; 1.1747x over previous
//
#include <hip/hip_runtime.h>
#include <hip/hip_bf16.h>
#include <cstdint>
#include <cstddef>

#define F_DIM 128
#define P_DIM 2048
#define RADIUS 4
#define HT_STRIDE 136   // ushorts per row: 272 B = 16B-aligned rows for b128 frag reads
#define LOG2E 1.4426950408889634f

typedef short s16x8 __attribute__((ext_vector_type(8)));
typedef float f32x4 __attribute__((ext_vector_type(4)));

static __device__ __forceinline__ float bf2f(ushort u) {
    union { float f; uint i; } v; v.i = ((uint)u) << 16; return v.f;
}
static __device__ __forceinline__ ushort f2bf(float f) {
    uint u = __float_as_uint(f);
    uint r = (u + 0x7fffu + ((u >> 16) & 1u)) >> 16;   // RTN-even
    return (ushort)r;
}
static __device__ __forceinline__ f32x4 mfma16(s16x8 a, s16x8 b, f32x4 c) {
    return __builtin_amdgcn_mfma_f32_16x16x32_bf16(a, b, c, 0, 0, 0);
}
// native v_exp_f32 / v_log_f32 (base-2). Args to ex2 are <= 0 after max-subtraction;
// flush-to-zero below 2^-126 matches softmax semantics (contribution ~0).
static __device__ __forceinline__ float ex2(float x) { return __builtin_amdgcn_exp2f(x); }
static __device__ __forceinline__ float lg2(float x) { return __builtin_amdgcn_logf(x); }

// ---------------- CSR build (once per launch) ----------------

__global__ void hist_kernel(const int* __restrict__ dst, int* __restrict__ counts, int E) {
    int e = blockIdx.x * blockDim.x + threadIdx.x;
    if (e < E) atomicAdd(&counts[dst[e]], 1);
}

__global__ __launch_bounds__(1024) void scan_kernel(const int* __restrict__ counts,
                                                    int* __restrict__ offs, int N) {
    __shared__ int buf[2][1024];
    __shared__ int carry_s;
    if (threadIdx.x == 0) carry_s = 0;
    __syncthreads();
    int nChunks = (N + 1023) >> 10;
    for (int c = 0; c < nChunks; ++c) {
        int i = (c << 10) + threadIdx.x;
        int v = (i < N) ? counts[i] : 0;
        int src = 0;
        buf[0][threadIdx.x] = v;
        __syncthreads();
        for (int off = 1; off < 1024; off <<= 1) {
            int d = src ^ 1;
            int val = buf[src][threadIdx.x];
            if (threadIdx.x >= (unsigned)off) val += buf[src][threadIdx.x - off];
            buf[d][threadIdx.x] = val;
            src = d;
            __syncthreads();
        }
        int inc = buf[src][threadIdx.x];
        if (i < N) offs[i + 1] = carry_s + inc;
        __syncthreads();
        if (threadIdx.x == 1023) carry_s += buf[src][1023];
        __syncthreads();
    }
    if (threadIdx.x == 0) offs[0] = 0;
}

__global__ void copy_kernel(const int* __restrict__ offs, int* __restrict__ cursor, int N) {
    int i = blockIdx.x * blockDim.x + threadIdx.x;
    if (i < N) cursor[i] = offs[i];
}

__global__ void scatter_kernel(const int* __restrict__ src, const int* __restrict__ dst,
                               int* __restrict__ cursor, int* __restrict__ srcs_sorted, int E) {
    int e = blockIdx.x * blockDim.x + threadIdx.x;
    if (e < E) {
        int d = dst[e];
        int pos = atomicAdd(&cursor[d], 1);
        srcs_sorted[pos] = src[e];
    }
}

// ---------------- one-time converts ----------------

__global__ void cvt_bf16_kernel(const float* __restrict__ src, ushort* __restrict__ dst, int n) {
    int i = blockIdx.x * blockDim.x + threadIdx.x;
    if (i < n) dst[i] = f2bf(src[i]);
}

__global__ void scale_kernel(const float* __restrict__ src, float* __restrict__ dst,
                             int n, float scale) {
    int i = blockIdx.x * blockDim.x + threadIdx.x;
    if (i < n) dst[i] = src[i] * scale;
}

// split fp32 W[K=128][P] (times scale) into hi+lo bf16, swizzled to MFMA B-frag order:
// dst[(((pt*4 + kt)*2 + s)*64 + lane)*8 + j] = split_s(scale*W[kt*32 + (lane>>4)*8 + j][pt*16 + (lane&15)])
__global__ void swizzle_split_kernel(const float* __restrict__ src, ushort* __restrict__ dst,
                                     int P, int total, float scale) {
    int d = blockIdx.x * blockDim.x + threadIdx.x;
    if (d >= total) return;
    int j    = d & 7;
    int lane = (d >> 3) & 63;
    int s    = (d >> 9) & 1;
    int kt   = (d >> 10) & 3;
    int pt   = d >> 12;
    int k = kt * 32 + (lane >> 4) * 8 + j;
    int p = pt * 16 + (lane & 15);
    float w = src[k * P + p] * scale;
    ushort hi = f2bf(w);
    ushort out = hi;
    if (s) out = f2bf(w - bf2f(hi));
    dst[d] = out;
}

// ---------------- aggregate (bf16 in, fp32 accum, bf16 out) ----------------
// 4 nodes per wave: quad q (16 lanes) owns one node; lane covers 16 B (uint4 = 8 bf16)
// of the 256 B row. 4 independent gather chains per wave -> 4x latency hiding and
// 1/4 the instructions vs the 1-node-per-wave version.

__global__ __launch_bounds__(256) void agg_kernel(const ushort* __restrict__ x,
                                                  const int* __restrict__ offs,
                                                  const int* __restrict__ srcs,
                                                  ushort* __restrict__ agg, int N) {
    int wid = (blockIdx.x * blockDim.x + threadIdx.x) >> 6;
    int lane = threadIdx.x & 63;
    int q = lane >> 4;
    int l16 = lane & 15;
    int node = wid * 4 + q;
    if (node >= N) return;
    const uint4* xr = (const uint4*)x;       // 16 uint4 per row
    uint4 v = xr[(size_t)node * 16 + l16];
    float acc[8];
    acc[0] = bf2f((ushort)(v.x & 0xffffu)); acc[1] = bf2f((ushort)(v.x >> 16));
    acc[2] = bf2f((ushort)(v.y & 0xffffu)); acc[3] = bf2f((ushort)(v.y >> 16));
    acc[4] = bf2f((ushort)(v.z & 0xffffu)); acc[5] = bf2f((ushort)(v.z >> 16));
    acc[6] = bf2f((ushort)(v.w & 0xffffu)); acc[7] = bf2f((ushort)(v.w >> 16));
    int e0 = offs[node], e1 = offs[node + 1];
    for (int e = e0; e < e1; ++e) {
        int j = srcs[e];
        uint4 u = xr[(size_t)j * 16 + l16];
        acc[0] += bf2f((ushort)(u.x & 0xffffu)); acc[1] += bf2f((ushort)(u.x >> 16));
        acc[2] += bf2f((ushort)(u.y & 0xffffu)); acc[3] += bf2f((ushort)(u.y >> 16));
        acc[4] += bf2f((ushort)(u.z & 0xffffu)); acc[5] += bf2f((ushort)(u.z >> 16));
        acc[6] += bf2f((ushort)(u.w & 0xffffu)); acc[7] += bf2f((ushort)(u.w >> 16));
    }
    uint4 o;
    o.x = ((uint)f2bf(acc[1]) << 16) | (uint)f2bf(acc[0]);
    o.y = ((uint)f2bf(acc[3]) << 16) | (uint)f2bf(acc[2]);
    o.z = ((uint)f2bf(acc[5]) << 16) | (uint)f2bf(acc[4]);
    o.w = ((uint)f2bf(acc[7]) << 16) | (uint)f2bf(acc[6]);
    ((uint4*)agg)[(size_t)node * 16 + l16] = o;
}

// ---------------- fused round ----------------
// block = 256 threads = 4 waves sharing ONE 64-node tile; wave w owns the P-range
// [32w, 32w+32). Barrier-free inner loops (round-10 skeleton). Single B buffer
// (~154 VGPRs, no spill at the (256,3) 170 cap). VALU diet vs round 10:
// native v_exp/v_log (exp2f/__log2f OCML guards cost ~8-12 instr each) and
// 32-bit pointer-bump addressing for the W2/b2 streams.

__global__ __launch_bounds__(256, 3) void round_kernel(
        const ushort* __restrict__ agg,    // [N,128] bf16
        const ushort* __restrict__ w1sw,   // swizzled hi/lo bf16 (natural scale)
        const float*  __restrict__ b1,
        const ushort* __restrict__ w2sw,   // swizzled hi/lo bf16, scaled by log2e
        const float*  __restrict__ b2l,    // b2 * log2e
        ushort* __restrict__ h_out,        // [N,128] bf16 (next round x)
        float* __restrict__ fp,            // [2048]
        int N) {
    __shared__ ushort smem_u[64 * HT_STRIDE];  // 17.4 KB; hT, later (m,s) merge buf
    ushort* hT = smem_u;
    float* mbuf = (float*)smem_u;              // [64][4] after hT is dead
    float* sbuf = ((float*)smem_u) + 256;      // [64][4]

    const int tid = threadIdx.x;
    const int w = tid >> 6;
    const int lane = tid & 63;
    const int q = lane >> 4;
    const int l15 = lane & 15;
    const int nodeBase = blockIdx.x * 64;
    const int ptBase = w * 32;

    const s16x8* w1v = (const s16x8*)w1sw;   // frag index: (pt*8 + kt*2 + s)*64 + lane
    const s16x8* w2v = (const s16x8*)w2sw;

    // ---- A-frags from global agg (all 4 waves load the same tile; L1-served) ----
    s16x8 a[4][4];
    #pragma unroll
    for (int g = 0; g < 4; ++g) {
        int node = nodeBase + g * 16 + l15;
        #pragma unroll
        for (int kt = 0; kt < 4; ++kt) {
            if (node < N)
                a[g][kt] = *(const s16x8*)(agg + (size_t)node * F_DIM + kt * 32 + q * 8);
            else
                a[g][kt] = (s16x8){0, 0, 0, 0, 0, 0, 0, 0};
        }
    }

    // ---- lin1: wave w computes feature tiles 2w, 2w+1 (h = relu(agg@W1+b1)) ----
    #pragma unroll
    for (int t = 0; t < 2; ++t) {
        int pt = 2 * w + t;
        f32x4 c[4];
        #pragma unroll
        for (int g = 0; g < 4; ++g) c[g] = (f32x4){0.f, 0.f, 0.f, 0.f};
        const s16x8* wp = w1v + pt * 8 * 64;
        #pragma unroll
        for (int kt = 0; kt < 4; ++kt) {
            s16x8 bh = wp[(kt * 2 + 0) * 64 + lane];
            s16x8 bl = wp[(kt * 2 + 1) * 64 + lane];
            #pragma unroll
            for (int g = 0; g < 4; ++g) {
                c[g] = mfma16(a[g][kt], bh, c[g]);
                c[g] = mfma16(a[g][kt], bl, c[g]);
            }
        }
        float bb = b1[pt * 16 + l15];
        #pragma unroll
        for (int g = 0; g < 4; ++g)
            #pragma unroll
            for (int r = 0; r < 4; ++r) {
                float v = c[g][r] + bb;
                v = v > 0.f ? v : 0.f;
                hT[(g * 16 + q * 4 + r) * HT_STRIDE + pt * 16 + l15] = f2bf(v);
            }
    }
    __syncthreads();

    // ---- coalesced hT -> h_out: 64 rows x 16 chunks over 256 threads ----
    #pragma unroll
    for (int it = 0; it < 4; ++it) {
        int idx = it * 256 + tid;      // 0..1023
        int row = idx >> 4;            // 0..63
        int chunk = idx & 15;          // 0..15
        int gnode = nodeBase + row;
        if (gnode < N) {
            s16x8 vv = *(const s16x8*)&hT[row * HT_STRIDE + chunk * 8];
            *(s16x8*)(h_out + (size_t)gnode * F_DIM + chunk * 8) = vv;
        }
    }

    // ---- lin2 A-frags from hT (reuse a[][]) ----
    #pragma unroll
    for (int g = 0; g < 4; ++g)
        #pragma unroll
        for (int kt = 0; kt < 4; ++kt)
            a[g][kt] = *(const s16x8*)&hT[(g * 16 + l15) * HT_STRIDE + kt * 32 + q * 8];
    __syncthreads();   // hT dead everywhere; allow (m,s) overlay

    // ---- pass 1: online max / sum-exp2 over the wave's 32 pts ----
    float m_[16], s_[16];
    #pragma unroll
    for (int j = 0; j < 16; ++j) { m_[j] = -INFINITY; s_[j] = 0.f; }

    {
        const s16x8* wp = w2v + ptBase * 8 * 64 + lane;   // bump by 512/iter
        const float* bp = b2l + ptBase * 16 + l15;        // bump by 16/iter
        for (int pti = 0; pti < 32; ++pti) {
            s16x8 b[8];
            #pragma unroll
            for (int f = 0; f < 8; ++f) b[f] = wp[f * 64];
            float bb = *bp;
            f32x4 c[4];
            #pragma unroll
            for (int g = 0; g < 4; ++g) c[g] = (f32x4){0.f, 0.f, 0.f, 0.f};
            #pragma unroll
            for (int kt = 0; kt < 4; ++kt) {
                #pragma unroll
                for (int g = 0; g < 4; ++g) c[g] = mfma16(a[g][kt], b[kt * 2 + 0], c[g]);
                #pragma unroll
                for (int g = 0; g < 4; ++g) c[g] = mfma16(a[g][kt], b[kt * 2 + 1], c[g]);
            }
            #pragma unroll
            for (int g = 0; g < 4; ++g)
                #pragma unroll
                for (int r = 0; r < 4; ++r) {
                    int j = g * 4 + r;
                    float v = c[g][r] + bb;
                    float d = v - m_[j];
                    float e = ex2(-fabsf(d));            // one exp per logit
                    float t1 = s_[j] + e;                // v <= m
                    float t2 = fmaf(s_[j], e, 1.0f);     // v >  m
                    bool up = d > 0.f;
                    s_[j] = up ? t2 : t1;
                    m_[j] = up ? v : m_[j];
                }
            wp += 512;
            bp += 16;
        }
    }

    // ---- intra-wave merge across 16 p-lanes; publish per-wave partials ----
    #pragma unroll
    for (int j = 0; j < 16; ++j) {
        float mm = m_[j], ss = s_[j];
        #pragma unroll
        for (int off = 1; off <= 8; off <<= 1) {
            float om = __shfl_xor(mm, off);
            float os = __shfl_xor(ss, off);
            float nm = fmaxf(mm, om);
            ss = ss * ex2(mm - nm) + os * ex2(om - nm);
            mm = nm;
        }
        if (l15 == 0) {
            int node = (j >> 2) * 16 + q * 4 + (j & 3);
            mbuf[node * 4 + w] = mm;
            sbuf[node * 4 + w] = ss;
        }
    }
    __syncthreads();

    // ---- cross-wave merge -> bbk = -m - log2(s) ----
    float bbk[16];
    #pragma unroll
    for (int j = 0; j < 16; ++j) {
        int node = (j >> 2) * 16 + q * 4 + (j & 3);
        float4 mv = *(const float4*)&mbuf[node * 4];
        float4 sv = *(const float4*)&sbuf[node * 4];
        float nm = fmaxf(fmaxf(mv.x, mv.y), fmaxf(mv.z, mv.w));
        float ss = sv.x * ex2(mv.x - nm) + sv.y * ex2(mv.y - nm)
                 + sv.z * ex2(mv.z - nm) + sv.w * ex2(mv.w - nm);
        bbk[j] = (nodeBase + node < N) ? (-nm - lg2(ss)) : -INFINITY;
    }

    // ---- pass 2: recompute the wave's 32 pts, atomics straight to global fp ----
    {
        const s16x8* wp = w2v + ptBase * 8 * 64 + lane;
        const float* bp = b2l + ptBase * 16 + l15;
        for (int pti = 0; pti < 32; ++pti) {
            int pt = ptBase + pti;
            s16x8 b[8];
            #pragma unroll
            for (int f = 0; f < 8; ++f) b[f] = wp[f * 64];
            float bb = *bp;
            f32x4 c[4];
            #pragma unroll
            for (int g = 0; g < 4; ++g) c[g] = (f32x4){0.f, 0.f, 0.f, 0.f};
            #pragma unroll
            for (int kt = 0; kt < 4; ++kt) {
                #pragma unroll
                for (int g = 0; g < 4; ++g) c[g] = mfma16(a[g][kt], b[kt * 2 + 0], c[g]);
                #pragma unroll
                for (int g = 0; g < 4; ++g) c[g] = mfma16(a[g][kt], b[kt * 2 + 1], c[g]);
            }
            float tot = 0.f;
            #pragma unroll
            for (int g = 0; g < 4; ++g)
                #pragma unroll
                for (int r = 0; r < 4; ++r)
                    tot += ex2(c[g][r] + bb + bbk[g * 4 + r]);
            tot += __shfl_xor(tot, 16);
            tot += __shfl_xor(tot, 32);
            if (lane < 16) atomicAdd(&fp[pt * 16 + lane], tot);
            wp += 512;
            bp += 16;
        }
    }
}

// ---------------- launcher ----------------

extern "C" void kernel_launch(void* const* d_in, const int* in_sizes, int n_in,
                              void* d_out, int out_size, void* d_ws, size_t ws_size,
                              hipStream_t stream) {
    const float* atoms = (const float*)d_in[0];
    const float* W1    = (const float*)d_in[1];
    const float* b1    = (const float*)d_in[2];
    const float* W2    = (const float*)d_in[3];
    const float* b2    = (const float*)d_in[4];
    const int* esrc    = (const int*)d_in[5];
    const int* edst    = (const int*)d_in[6];
    float* fp          = (float*)d_out;
    const int N = in_sizes[0] / F_DIM;
    const int E = in_sizes[5];

    char* ws = (char*)d_ws;
    ushort* xA   = (ushort*)ws;  ws += (size_t)N * F_DIM * sizeof(ushort);
    ushort* xB   = (ushort*)ws;  ws += (size_t)N * F_DIM * sizeof(ushort);
    ushort* aggb = (ushort*)ws;  ws += (size_t)N * F_DIM * sizeof(ushort);
    ushort* w1sw = (ushort*)ws;  ws += (size_t)F_DIM * F_DIM * 2 * sizeof(ushort);
    ushort* w2sw = (ushort*)ws;  ws += (size_t)F_DIM * P_DIM * 2 * sizeof(ushort);
    float*  b2l  = (float*)ws;   ws += (size_t)P_DIM * sizeof(float);
    int* offs    = (int*)ws;     ws += (((size_t)(N + 1) * sizeof(int) + 255) & ~255ull);
    int* cursor  = (int*)ws;     ws += (((size_t)N * sizeof(int) + 255) & ~255ull);
    int* srcs    = (int*)ws;

    hipMemsetAsync(d_out, 0, (size_t)out_size * sizeof(float), stream);
    hipMemsetAsync(cursor, 0, (size_t)N * sizeof(int), stream);

    // CSR build
    int eb = (E + 255) / 256;
    hist_kernel<<<eb, 256, 0, stream>>>(edst, cursor, E);
    scan_kernel<<<1, 1024, 0, stream>>>(cursor, offs, N);
    copy_kernel<<<(N + 255) / 256, 256, 0, stream>>>(offs, cursor, N);
    scatter_kernel<<<eb, 256, 0, stream>>>(esrc, edst, cursor, srcs, E);

    // one-time converts
    int nconv = N * F_DIM;
    cvt_bf16_kernel<<<(nconv + 255) / 256, 256, 0, stream>>>(atoms, xA, nconv);
    int t1 = F_DIM * F_DIM * 2;
    swizzle_split_kernel<<<(t1 + 255) / 256, 256, 0, stream>>>(W1, w1sw, F_DIM, t1, 1.0f);
    int t2 = F_DIM * P_DIM * 2;
    swizzle_split_kernel<<<(t2 + 255) / 256, 256, 0, stream>>>(W2, w2sw, P_DIM, t2, LOG2E);
    scale_kernel<<<(P_DIM + 255) / 256, 256, 0, stream>>>(b2, b2l, P_DIM, LOG2E);

    const ushort* x = xA;
    ushort* xnext = xB;
    int rblocks = (N + 63) / 64;
    int ablocks = (N + 15) / 16;   // 16 nodes per 256-thread block (4/wave)
    for (int r = 0; r < RADIUS; ++r) {
        agg_kernel<<<ablocks, 256, 0, stream>>>(x, offs, srcs, aggb, N);
        round_kernel<<<rblocks, 256, 0, stream>>>(aggb, w1sw, b1, w2sw, b2l,
                                                  xnext, fp, N);
        x = xnext;
        xnext = (xnext == xB) ? xA : xB;
    }
}